// Round 2
// baseline (652.866 us; speedup 1.0000x reference)
//
#include <hip/hip_runtime.h>
#include <math.h>

// Problem constants
#define BATCH 2
#define SEQ   2048
#define DIM   2048
#define NH    16
#define HD    128
#define EPS   1e-6f

typedef _Float16 f16x8 __attribute__((ext_vector_type(8)));
typedef _Float16 f16x4 __attribute__((ext_vector_type(4)));
typedef _Float16 f16x2 __attribute__((ext_vector_type(2)));
typedef float    f32x4 __attribute__((ext_vector_type(4)));

#define MFMA_F16 __builtin_amdgcn_mfma_f32_16x16x32_f16

// W pre-scale: W*1024 keeps W_lo (~2^-12 * 0.02) in fp16 normal range.
#define WSCALE    1024.0f
#define INV_WSCALE 0.0009765625f

// Both GEMMs have K = 2048; compile-time for addressing.
#define GK 2048

// ---------------------------------------------------------------------------
// fp32 -> fp16 (single), 4 el/thread
// ---------------------------------------------------------------------------
__global__ __launch_bounds__(256) void cvt_f16(
    const float* __restrict__ in, _Float16* __restrict__ out) {
  int i = blockIdx.x * 256 + threadIdx.x;
  float4 v = ((const float4*)in)[i];
  f16x4 o;
  o[0] = (_Float16)v.x; o[1] = (_Float16)v.y;
  o[2] = (_Float16)v.z; o[3] = (_Float16)v.w;
  ((f16x4*)out)[i] = o;
}

// ---------------------------------------------------------------------------
// fp32 -> (hi, lo) fp16 of value*1024 (weights)
// ---------------------------------------------------------------------------
__global__ __launch_bounds__(256) void split_f16s(
    const float* __restrict__ in, _Float16* __restrict__ hi,
    _Float16* __restrict__ lo) {
  int i = blockIdx.x * 256 + threadIdx.x;
  float4 v = ((const float4*)in)[i];
  f16x4 h, l;
  float s;
  s = v.x * WSCALE; h[0] = (_Float16)s; l[0] = (_Float16)(s - (float)h[0]);
  s = v.y * WSCALE; h[1] = (_Float16)s; l[1] = (_Float16)(s - (float)h[1]);
  s = v.z * WSCALE; h[2] = (_Float16)s; l[2] = (_Float16)(s - (float)h[2]);
  s = v.w * WSCALE; h[3] = (_Float16)s; l[3] = (_Float16)(s - (float)h[3]);
  ((f16x4*)hi)[i] = h;
  ((f16x4*)lo)[i] = l;
}

// ---------------------------------------------------------------------------
// 2-pass fp16 MFMA GEMM, per-wave 128x64 output, 2 blocks/CU.
//   C[M,N] = A[M,K] @ (Bh+Bl)[N,K]^T * outscale
// BM=256, BN template (128 QKV / 64 proj), BK=32, 4 waves (2x2).
// LDS: 2 buf x (BM + 2*BN) rows x 32 f16 = 64/48 KiB -> 2 blocks/CU (TLP).
// Per K-tile: 1 vmcnt(0)+barrier; stage next tile early (full-tile cover);
// 16(12) ds_read_b128 feed 64(32) MFMA -> 64 FLOP/LDS-byte (1.5x prev).
// Swizzle both-sides: global source slot ^= row&3 (64B rows), linear LDS
// dest (global_load_lds), same XOR on ds_read slots.  Grid: QKV 768 = 3/CU
// exact, proj 512 = 2/CU exact.
// ---------------------------------------------------------------------------
template <int BN>
__global__ __launch_bounds__(256, 2) void gemm_w64(
    const _Float16* __restrict__ Ag, const _Float16* __restrict__ Bhg,
    const _Float16* __restrict__ Blg, float* __restrict__ C,
    int M, int N, float outscale) {
  constexpr int BM = 256;
  constexpr int BK = 32;
  constexpr int ROWS = BM + 2 * BN;          // A rows + Bh rows + Bl rows
  constexpr int NCPW = ROWS / 16 / 4;        // staging chunks per wave (8/6)
  constexpr int NR = BN / 32;                // B-frags per wave (4/2)
  __shared__ __align__(16) _Float16 smem[2][ROWS][BK];

  const int t = threadIdx.x;
  const int w = t >> 6, lane = t & 63;
  const int bm = blockIdx.y * BM, bn = blockIdx.x * BN;
  const int wr = (w >> 1) * 128;             // wave row: 2 rows of waves
  const int wc = (w & 1) * (BN / 2);         // wave col: 2 cols of waves
  const int quad = lane >> 4, c15 = lane & 15;
  // swizzled 16B-slot -> f16 col for fragment reads (row&3 == c15&3 for all
  // fragment rows: wr, wc, 16*m, BM, BM+BN are all == 0 mod 4)
  const int colr = (quad ^ (c15 & 3)) * 8;

  // staging per-lane setup: chunk = 16 rows x 64B; lane covers row l>>2,
  // slot l&3; global source pre-swizzled so LDS[row][s] = G[row][s^(row&3)]
  const int l2 = lane >> 2, l4 = lane & 3;
  const int gsw = (l4 ^ (l2 & 3)) * 8;       // f16 units
  const _Float16* pc[NCPW];
  #pragma unroll
  for (int e = 0; e < NCPW; ++e) {
    int ch = w * NCPW + e;
    int row = ch * 16 + l2;
    const _Float16* s;
    if (row < BM)            s = Ag  + (size_t)(bm + row) * GK;
    else if (row < BM + BN)  s = Bhg + (size_t)(bn + row - BM) * GK;
    else                     s = Blg + (size_t)(bn + row - BM - BN) * GK;
    pc[e] = s + gsw;
  }

  f32x4 acc[8][NR] = {};

#define STAGE(buf)                                                            \
  _Pragma("unroll")                                                           \
  for (int e = 0; e < NCPW; ++e) {                                            \
    __builtin_amdgcn_global_load_lds(                                         \
        (const __attribute__((address_space(1))) unsigned int*)pc[e],         \
        (__attribute__((address_space(3))) unsigned int*)                     \
            (&smem[buf][(w * NCPW + e) * 16][0]),                             \
        16, 0, 0);                                                            \
    pc[e] += BK;                                                              \
  }

  // One barrier + one vmcnt per K-tile.  Order: drain own loads for the
  // buffer about to be read -> barrier (now everyone's loads landed, and
  // everyone is done reading the other buffer) -> issue next-tile stage
  // (targets the buffer last read one tile ago) -> ds_read -> MFMA.
#define TILE(buf, dostage)                                                    \
  {                                                                           \
    asm volatile("s_waitcnt vmcnt(0)" ::: "memory");                          \
    __builtin_amdgcn_sched_barrier(0);                                        \
    __builtin_amdgcn_s_barrier();                                             \
    __builtin_amdgcn_sched_barrier(0);                                        \
    if (dostage) { STAGE(1 - (buf)) }                                         \
    f16x8 a[8], bhf[NR], blf[NR];                                             \
    _Pragma("unroll")                                                         \
    for (int m = 0; m < 8; ++m)                                               \
      a[m] = *(const f16x8*)(&smem[buf][wr + m * 16 + c15][colr]);            \
    _Pragma("unroll")                                                         \
    for (int n = 0; n < NR; ++n) {                                            \
      bhf[n] = *(const f16x8*)(&smem[buf][BM + wc + n * 16 + c15][colr]);     \
      blf[n] = *(const f16x8*)(&smem[buf][BM + BN + wc + n * 16 + c15][colr]);\
    }                                                                         \
    __builtin_amdgcn_s_setprio(1);                                            \
    _Pragma("unroll")                                                         \
    for (int m = 0; m < 8; ++m)                                               \
      _Pragma("unroll")                                                       \
      for (int n = 0; n < NR; ++n)                                            \
        acc[m][n] = MFMA_F16(a[m], bhf[n], acc[m][n], 0, 0, 0);               \
    _Pragma("unroll")                                                         \
    for (int m = 0; m < 8; ++m)                                               \
      _Pragma("unroll")                                                       \
      for (int n = 0; n < NR; ++n)                                            \
        acc[m][n] = MFMA_F16(a[m], blf[n], acc[m][n], 0, 0, 0);               \
    __builtin_amdgcn_s_setprio(0);                                            \
  }

  STAGE(0)                       // prologue: tile 0 -> buf0
  const int NT = GK / BK;        // 64 (even)
  for (int tt = 0; tt < NT; tt += 2) {
    TILE(0, true)                       // reads buf0, stages tile tt+1 -> buf1
    TILE(1, (tt + 2 < NT))              // reads buf1, stages tile tt+2 -> buf0
  }

  // C/D layout: col = lane&15, row = (lane>>4)*4 + reg
  #pragma unroll
  for (int m = 0; m < 8; ++m)
    #pragma unroll
    for (int n = 0; n < NR; ++n) {
      int col = bn + wc + 16 * n + c15;
      #pragma unroll
      for (int r = 0; r < 4; ++r) {
        int row = bm + wr + 16 * m + quad * 4 + r;
        C[(size_t)row * N + col] = acc[m][n][r] * outscale;
      }
    }
#undef STAGE
#undef TILE
}

// ---------------------------------------------------------------------------
// RMSNorm + RoPE on q,k of qkv[b,s,6144]; emits Q fp16 (single) and K hi/lo
// fp16, layout [b,h,s,d].
// ---------------------------------------------------------------------------
__global__ __launch_bounds__(256) void rmsrope_f16(
    const float* __restrict__ qkv, const float* __restrict__ cosb,
    const float* __restrict__ sinb, _Float16* __restrict__ Qg,
    _Float16* __restrict__ Khg, _Float16* __restrict__ Klg) {
  const int blk = blockIdx.x;           // b*SEQ + s
  const int b = blk >> 11, s = blk & (SEQ - 1);
  const int wave = threadIdx.x >> 6, lane = threadIdx.x & 63;
  const float* base = qkv + (size_t)blk * (3 * DIM);
  const float c  = cosb[s * HD + 2 * lane];
  const float sn = sinb[s * HD + 2 * lane];
  #pragma unroll
  for (int h = wave; h < NH; h += 4) {
    float2 q = *(const float2*)(base + h * HD + 2 * lane);
    float2 k = *(const float2*)(base + DIM + h * HD + 2 * lane);
    float ssq = q.x * q.x + q.y * q.y;
    float ssk = k.x * k.x + k.y * k.y;
    #pragma unroll
    for (int off = 32; off >= 1; off >>= 1) {
      ssq += __shfl_xor(ssq, off, 64);
      ssk += __shfl_xor(ssk, off, 64);
    }
    float rq = rsqrtf(ssq * (1.0f / HD) + EPS);
    float rk = rsqrtf(ssk * (1.0f / HD) + EPS);
    float q1 = q.x * rq, q2 = q.y * rq;
    float k1 = k.x * rk, k2 = k.y * rk;
    float qy1 = q1 * c - q2 * sn, qy2 = q1 * sn + q2 * c;
    float ky1 = k1 * c - k2 * sn, ky2 = k1 * sn + k2 * c;
    size_t o = ((size_t)(b * NH + h) * SEQ + s) * HD + 2 * lane;
    f16x2 qo, kh, kl;
    qo[0] = (_Float16)qy1; qo[1] = (_Float16)qy2;
    kh[0] = (_Float16)ky1; kl[0] = (_Float16)(ky1 - (float)kh[0]);
    kh[1] = (_Float16)ky2; kl[1] = (_Float16)(ky2 - (float)kh[1]);
    *(f16x2*)(Qg  + o) = qo;
    *(f16x2*)(Khg + o) = kh;
    *(f16x2*)(Klg + o) = kl;
  }
}

// ---------------------------------------------------------------------------
// V transpose: qkv v-slice [64 s][128 d] fp32 -> Vt [b,h,d,s] single fp16.
// ---------------------------------------------------------------------------
__global__ __launch_bounds__(256) void vtrans_f16(
    const float* __restrict__ qkv, _Float16* __restrict__ Vt) {
  __shared__ _Float16 L[64 * 132];
  const int t = threadIdx.x;
  const int s0 = blockIdx.x * 64, h = blockIdx.y, b = blockIdx.z;
  const float* src = qkv + ((size_t)(b * SEQ + s0)) * (3 * DIM) + 2 * DIM + h * HD;
  #pragma unroll
  for (int it = 0; it < 8; ++it) {
    int f = t + it * 256;
    int r = f >> 5, c4 = f & 31;
    float4 v = *(const float4*)(src + (size_t)r * (3 * DIM) + c4 * 4);
    f16x4 o;
    o[0] = (_Float16)v.x; o[1] = (_Float16)v.y;
    o[2] = (_Float16)v.z; o[3] = (_Float16)v.w;
    *(f16x4*)(&L[r * 132 + c4 * 4]) = o;
  }
  __syncthreads();
  const int d = t >> 1, sc = (t & 1) * 32;
  size_t dst = ((size_t)((b * NH + h) * HD + d)) * SEQ + s0 + sc;
  #pragma unroll
  for (int j = 0; j < 8; ++j) {
    f16x4 o;
    o[0] = L[(sc + 4 * j + 0) * 132 + d];
    o[1] = L[(sc + 4 * j + 1) * 132 + d];
    o[2] = L[(sc + 4 * j + 2) * 132 + d];
    o[3] = L[(sc + 4 * j + 3) * 132 + d];
    *(f16x4*)(Vt + dst + j * 4) = o;
  }
}

// ---------------------------------------------------------------------------
// fp16 MFMA flash attention, fixed-max softmax.
// QK^T: Q single fp16 x (Kh + Kl) = 2 passes.  PV: P fp16 x V fp16 = 1 pass.
// 48 MFMA / K-chunk.  LDS: Kh/Kl/Vt 8 KB each + P 10 KB = 34 KB.
// ---------------------------------------------------------------------------
#define QT 128
#define KC 32

__global__ __launch_bounds__(256, 2) void flash_f16(
    const _Float16* __restrict__ Qg, const _Float16* __restrict__ Khg,
    const _Float16* __restrict__ Klg, const _Float16* __restrict__ Vtg,
    _Float16* __restrict__ Og) {
  // shorts(f16): Kh [0,4096)  Kl [4096,8192)  Vt [8192,12288)
  // P [12288,17408): per wave [32][40].  Q staging reuses [0,16384).
  __shared__ __align__(16) _Float16 sm[17408];

  const int t = threadIdx.x, w = t >> 6, lane = t & 63;
  const int quad = lane >> 4, c15 = lane & 15;
  const int hy = blockIdx.y, bz = blockIdx.z;
  const int bh = bz * NH + hy;
  const int q0 = blockIdx.x * QT;
  const int wr = w * 32;

  // ---- stage Q [128][128] f16 once; fragments -> registers ----
  {
    const _Float16* qsrc = Qg + ((size_t)bh * SEQ + q0) * HD;
    #pragma unroll
    for (int p = 0; p < 8; ++p) {
      int ci = p * 256 + t;
      int r = ci >> 4, c8 = (ci & 15) ^ (r & 15);
      __builtin_amdgcn_global_load_lds(
          (const __attribute__((address_space(1))) unsigned int*)(qsrc + (size_t)r * HD + c8 * 8),
          (__attribute__((address_space(3))) unsigned int*)(sm + ci * 8), 16, 0, 0);
    }
  }
  __syncthreads();
  f16x8 qf[2][4];  // [mf][ks]
  #pragma unroll
  for (int mf = 0; mf < 2; ++mf)
    #pragma unroll
    for (int ks = 0; ks < 4; ++ks) {
      int m = wr + mf * 16 + c15;
      int c8 = ks * 4 + quad;
      qf[mf][ks] = *(const f16x8*)(sm + (m * 16 + (c8 ^ (m & 15))) * 8);
    }

  float lrow[8];
  f32x4 oacc[2][8];
  #pragma unroll
  for (int i = 0; i < 8; ++i) lrow[i] = 0.f;
  #pragma unroll
  for (int mf = 0; mf < 2; ++mf)
    #pragma unroll
    for (int nf = 0; nf < 8; ++nf) oacc[mf][nf] = (f32x4){0.f, 0.f, 0.f, 0.f};

  const float sl = 0.12751744f;       // (1/sqrt(128)) * log2(e)
  const float M2 = 16.322231f;        // sqrt(128) * log2(e)  (|score|<=sqrt(128))
  _Float16* Pw = sm + 12288 + w * 1280;

  for (int kk = 0; kk < SEQ; kk += KC) {
    __syncthreads();  // all waves done with previous tiles (and Q frags at kk=0)
    if (w == 0 || w == 1) {   // Kh / Kl tiles [32][128]
      const _Float16* src = (w == 0 ? Khg : Klg) + ((size_t)bh * SEQ + kk) * HD;
      #pragma unroll
      for (int p = 0; p < 8; ++p) {
        int ci = p * 64 + lane;
        int r = ci >> 4, c8 = (ci & 15) ^ (r & 15);
        __builtin_amdgcn_global_load_lds(
            (const __attribute__((address_space(1))) unsigned int*)(src + (size_t)r * HD + c8 * 8),
            (__attribute__((address_space(3))) unsigned int*)(sm + w * 4096 + ci * 8), 16, 0, 0);
      }
    } else if (w == 2) {      // V^T tile [128 d][32 s]
      const _Float16* src = Vtg + (size_t)bh * HD * SEQ + kk;
      #pragma unroll
      for (int p = 0; p < 8; ++p) {
        int ci = p * 64 + lane;
        int d = ci >> 2, c8 = (ci & 3) ^ (d & 3);
        __builtin_amdgcn_global_load_lds(
            (const __attribute__((address_space(1))) unsigned int*)(src + (size_t)d * SEQ + c8 * 8),
            (__attribute__((address_space(3))) unsigned int*)(sm + 8192 + ci * 8), 16, 0, 0);
      }
    }
    __syncthreads();

    // ---- S = Q K^T (2 passes: Kh then Kl) ----
    f32x4 accs[2][2] = {};
    #pragma unroll
    for (int nf = 0; nf < 2; ++nf) {
      f16x8 kh[4], kl[4];
      #pragma unroll
      for (int ks = 0; ks < 4; ++ks) {
        int n = nf * 16 + c15;
        int c8 = ks * 4 + quad;
        int slot = (n * 16 + (c8 ^ (n & 15))) * 8;
        kh[ks] = *(const f16x8*)(sm + slot);
        kl[ks] = *(const f16x8*)(sm + 4096 + slot);
      }
      #pragma unroll
      for (int ks = 0; ks < 4; ++ks) {
        accs[0][nf] = MFMA_F16(qf[0][ks], kh[ks], accs[0][nf], 0, 0, 0);
        accs[1][nf] = MFMA_F16(qf[1][ks], kh[ks], accs[1][nf], 0, 0, 0);
      }
      #pragma unroll
      for (int ks = 0; ks < 4; ++ks) {
        accs[0][nf] = MFMA_F16(qf[0][ks], kl[ks], accs[0][nf], 0, 0, 0);
        accs[1][nf] = MFMA_F16(qf[1][ks], kl[ks], accs[1][nf], 0, 0, 0);
      }
    }

    // ---- fixed-shift softmax weights (lane-local denominator) ----
    #pragma unroll
    for (int mf = 0; mf < 2; ++mf)
      #pragma unroll
      for (int reg = 0; reg < 4; ++reg) {
        float p0 = exp2f(fmaf(accs[mf][0][reg], sl, -M2));
        float p1 = exp2f(fmaf(accs[mf][1][reg], sl, -M2));
        lrow[mf * 4 + reg] += p0 + p1;
        int prow = mf * 16 + quad * 4 + reg;
        Pw[prow * 40 + c15]      = (_Float16)p0;
        Pw[prow * 40 + c15 + 16] = (_Float16)p1;
      }

    // ---- O += P V (single pass) ----
    f16x8 pa0 = *(const f16x8*)(Pw + (c15) * 40 + quad * 8);
    f16x8 pa1 = *(const f16x8*)(Pw + (16 + c15) * 40 + quad * 8);
    #pragma unroll
    for (int nf = 0; nf < 8; ++nf) {
      int dd = nf * 16 + c15;
      int slot = (dd * 4 + (quad ^ (dd & 3))) * 8;
      f16x8 vv = *(const f16x8*)(sm + 8192 + slot);
      oacc[0][nf] = MFMA_F16(pa0, vv, oacc[0][nf], 0, 0, 0);
      oacc[1][nf] = MFMA_F16(pa1, vv, oacc[1][nf], 0, 0, 0);
    }
  }

  // ---- epilogue: denominator reduce + O write (single fp16) ----
  #pragma unroll
  for (int i = 0; i < 8; ++i) {
    float s = lrow[i];
    #pragma unroll
    for (int off = 8; off >= 1; off >>= 1) s += __shfl_xor(s, off, 64);
    lrow[i] = s;
  }
  #pragma unroll
  for (int mf = 0; mf < 2; ++mf)
    #pragma unroll
    for (int reg = 0; reg < 4; ++reg) {
      float inv = 1.0f / lrow[mf * 4 + reg];
      int row = q0 + wr + mf * 16 + quad * 4 + reg;
      size_t ob = ((size_t)bz * SEQ + row) * DIM + hy * HD + c15;
      #pragma unroll
      for (int nf = 0; nf < 8; ++nf)
        Og[ob + nf * 16] = (_Float16)(oacc[mf][nf][reg] * inv);
    }
}

// ---------------------------------------------------------------------------
// Launch.  Workspace (<= 201 MB):
//   [0, 100663296)          qkv fp32 -> later O16 + Wph/Wpl
//   R = +100663296:
//     pre-gemm1 : x16 [R,+16.7M)  Wh [R+16.7M,+25.2M)  Wl [R+41.9M,+25.2M)
//     post-gemm1: Q16 [R) Kh [R+16.7M) Kl [R+33.6M) Vt [R+50.3M) (16.7M each)
//   O16 at ws[0,16.7M), Wph ws+16.7M, Wpl ws+25.2M (after qkv consumed).
// ---------------------------------------------------------------------------
extern "C" void kernel_launch(void* const* d_in, const int* in_sizes, int n_in,
                              void* d_out, int out_size, void* d_ws, size_t ws_size,
                              hipStream_t stream) {
  const float* x     = (const float*)d_in[0];
  const float* cosb  = (const float*)d_in[1];
  const float* sinb  = (const float*)d_in[2];
  const float* Wqkv  = (const float*)d_in[3];
  const float* Wproj = (const float*)d_in[4];
  float* out = (float*)d_out;

  char* ws = (char*)d_ws;
  float* qkv = (float*)ws;
  char* R = ws + 100663296;
  _Float16* x16 = (_Float16*)(R);
  _Float16* Wh  = (_Float16*)(R + 16777216);
  _Float16* Wl  = (_Float16*)(R + 41943040);
  _Float16* Q16 = (_Float16*)(R);
  _Float16* Kh  = (_Float16*)(R + 16777216);
  _Float16* Kl  = (_Float16*)(R + 33554432);
  _Float16* Vt  = (_Float16*)(R + 50331648);
  _Float16* O16 = (_Float16*)(ws);
  _Float16* Wph = (_Float16*)(ws + 16777216);
  _Float16* Wpl = (_Float16*)(ws + 25165824);

  cvt_f16  <<<8192,  256, 0, stream>>>(x, x16);
  split_f16s<<<12288, 256, 0, stream>>>(Wqkv, Wh, Wl);
  gemm_w64<128><<<dim3(48, 16), 256, 0, stream>>>(x16, Wh, Wl, qkv, 4096, 6144, INV_WSCALE);
  rmsrope_f16<<<4096, 256, 0, stream>>>(qkv, cosb, sinb, Q16, Kh, Kl);
  vtrans_f16<<<dim3(32, NH, BATCH), 256, 0, stream>>>(qkv, Vt);
  split_f16s<<<4096, 256, 0, stream>>>(Wproj, Wph, Wpl);   // after qkv consumed
  flash_f16<<<dim3(SEQ / QT, NH, BATCH), 256, 0, stream>>>(Q16, Kh, Kl, Vt, O16);
  gemm_w64<64><<<dim3(32, 16), 256, 0, stream>>>(O16, Wph, Wpl, out, 4096, 2048, INV_WSCALE);
}

// Round 3
// 529.033 us; speedup vs baseline: 1.2341x; 1.2341x over previous
//
#include <hip/hip_runtime.h>
#include <math.h>

// Problem constants
#define BATCH 2
#define SEQ   2048
#define DIM   2048
#define NH    16
#define HD    128
#define EPS   1e-6f

typedef _Float16 f16x8 __attribute__((ext_vector_type(8)));
typedef _Float16 f16x4 __attribute__((ext_vector_type(4)));
typedef _Float16 f16x2 __attribute__((ext_vector_type(2)));
typedef float    f32x4 __attribute__((ext_vector_type(4)));

#define MFMA_F16 __builtin_amdgcn_mfma_f32_16x16x32_f16

// W pre-scale: W*1024 keeps W_lo (~2^-12 * 0.02) in fp16 normal range.
#define WSCALE    1024.0f
#define INV_WSCALE 0.0009765625f

// ---------------------------------------------------------------------------
// fp32 -> fp16 (single), 4 el/thread
// ---------------------------------------------------------------------------
__global__ __launch_bounds__(256) void cvt_f16(
    const float* __restrict__ in, _Float16* __restrict__ out) {
  int i = blockIdx.x * 256 + threadIdx.x;
  float4 v = ((const float4*)in)[i];
  f16x4 o;
  o[0] = (_Float16)v.x; o[1] = (_Float16)v.y;
  o[2] = (_Float16)v.z; o[3] = (_Float16)v.w;
  ((f16x4*)out)[i] = o;
}

// ---------------------------------------------------------------------------
// fp32 -> (hi, lo) fp16 of value*1024 (weights)
// ---------------------------------------------------------------------------
__global__ __launch_bounds__(256) void split_f16s(
    const float* __restrict__ in, _Float16* __restrict__ hi,
    _Float16* __restrict__ lo) {
  int i = blockIdx.x * 256 + threadIdx.x;
  float4 v = ((const float4*)in)[i];
  f16x4 h, l;
  float s;
  s = v.x * WSCALE; h[0] = (_Float16)s; l[0] = (_Float16)(s - (float)h[0]);
  s = v.y * WSCALE; h[1] = (_Float16)s; l[1] = (_Float16)(s - (float)h[1]);
  s = v.z * WSCALE; h[2] = (_Float16)s; l[2] = (_Float16)(s - (float)h[2]);
  s = v.w * WSCALE; h[3] = (_Float16)s; l[3] = (_Float16)(s - (float)h[3]);
  ((f16x4*)hi)[i] = h;
  ((f16x4*)lo)[i] = l;
}

// ---------------------------------------------------------------------------
// 8-phase 2-pass fp16 MFMA GEMM (round-1 proven: 180us QKV, MfmaUtil 51%,
// zero bank conflicts).  BM=256 BN=128 BK=64, 8 waves (2x4).
// LDS: 2 buf x (A 256x64 + Bh 128x64 + Bl 128x64) f16 = 128 KiB.
// Counted vmcnt(2) at ph0/1/4/5; swizzle chunk^=row&7 within 128B rows on
// global source + ds_read addrs (LDS dest linear).
// ---------------------------------------------------------------------------
#define BM8 256
#define BN8 128

__global__ __launch_bounds__(512, 2) void gemm_2p8(
    const _Float16* __restrict__ Ag, const _Float16* __restrict__ Bhg,
    const _Float16* __restrict__ Blg, float* __restrict__ C,
    int M, int N, int K, float outscale) {
  // stack rows: [0,256) = A, [256,384) = Bh, [384,512) = Bl; 64 f16 per row.
  __shared__ __align__(16) _Float16 smem[2][512][64];

  const int t = threadIdx.x;
  const int w = t >> 6, lane = t & 63;
  const int bm = blockIdx.y * BM8, bn = blockIdx.x * BN8;
  const int wr = (w >> 2) * 128;      // wave row offset (2 wave-rows)
  const int wc = (w & 3) * 32;        // wave col offset (4 wave-cols)
  const int quad = lane >> 4, c15 = lane & 15;

  const _Float16* baseA  = Ag  + (size_t)bm * K;
  const _Float16* baseBh = Bhg + (size_t)bn * K;
  const _Float16* baseBl = Blg + (size_t)bn * K;

  const int lrow = lane >> 3;
  const int lswz = ((lane & 7) ^ lrow) * 8;    // f16 units

  const int col0 = (((0 * 4) + quad) ^ (c15 & 7)) * 8;   // ks=0
  const int col1 = (((1 * 4) + quad) ^ (c15 & 7)) * 8;   // ks=1

  f32x4 acc[8][2] = {};
  f16x8 a0[8], a1[8], bh[2][2], bl[2][2];

#define STAGE2(buf, q, kofs)                                                   \
  {                                                                            \
    _Pragma("unroll")                                                          \
    for (int e = 0; e < 2; ++e) {                                              \
      int c = (q) * 16 + 2 * w + e;                                            \
      int rl = c * 8 + lrow;                                                   \
      const _Float16* g;                                                       \
      if ((q) < 2)        g = baseA  + (size_t)rl * K;                         \
      else if ((q) == 2)  g = baseBh + (size_t)(rl - 256) * K;                 \
      else                g = baseBl + (size_t)(rl - 384) * K;                 \
      __builtin_amdgcn_global_load_lds(                                        \
          (const __attribute__((address_space(1))) unsigned int*)(g + (kofs) + lswz), \
          (__attribute__((address_space(3))) unsigned int*)(&smem[buf][(c) * 8][0]),  \
          16, 0, 0);                                                           \
    }                                                                          \
  }

#define LDA8(dst, colv, buf)                                                   \
  _Pragma("unroll")                                                            \
  for (int m2 = 0; m2 < 8; ++m2)                                               \
    dst[m2] = *(const f16x8*)(&smem[buf][wr + m2 * 16 + c15][colv]);

#define LDB2(dst, rbase, colv, buf)                                            \
  _Pragma("unroll")                                                            \
  for (int n2 = 0; n2 < 2; ++n2)                                               \
    dst[n2] = *(const f16x8*)(&smem[buf][(rbase) + wc + n2 * 16 + c15][colv]);

#define MF16(af, bf)                                                           \
  _Pragma("unroll")                                                            \
  for (int m2 = 0; m2 < 8; ++m2)                                               \
    _Pragma("unroll")                                                          \
    for (int n2 = 0; n2 < 2; ++n2)                                             \
      acc[m2][n2] = MFMA_F16(af[m2], bf[n2], acc[m2][n2], 0, 0, 0);

#define PH_TOP()                                                               \
  __builtin_amdgcn_s_barrier();                                                \
  __builtin_amdgcn_sched_barrier(0);

  // prologue: tile 0 -> buf0 (issue order: A-low, A-high, Bh, Bl)
  STAGE2(0, 0, 0) STAGE2(0, 1, 0) STAGE2(0, 2, 0) STAGE2(0, 3, 0)

  const int NI = K >> 7;   // 2 K-tiles per iter
  for (int i = 0; i < NI; ++i) {
    const int kB = (i << 7) + 64;     // buf1 tile (staged ph0-3)
    const int kN = (i << 7) + 128;    // next buf0 tile (staged ph4-7)
    const bool more = (i + 1 < NI);

    // ---- ph0: buf0 pass-h ks0 ----
    asm volatile("s_waitcnt vmcnt(2)" ::: "memory");
    PH_TOP();
    LDA8(a0, col0, 0);
    LDB2(bh[0], 256, col0, 0);
    STAGE2(1, 0, kB);
    __builtin_amdgcn_s_setprio(1);
    MF16(a0, bh[0]);
    __builtin_amdgcn_s_setprio(0);

    // ---- ph1: buf0 pass-h ks1 ----
    asm volatile("s_waitcnt vmcnt(2)" ::: "memory");
    PH_TOP();
    LDA8(a1, col1, 0);
    LDB2(bh[1], 256, col1, 0);
    STAGE2(1, 1, kB);
    __builtin_amdgcn_s_setprio(1);
    MF16(a1, bh[1]);
    __builtin_amdgcn_s_setprio(0);

    // ---- ph2: buf0 pass-l ks0 ----
    PH_TOP();
    LDB2(bl[0], 384, col0, 0);
    STAGE2(1, 2, kB);
    __builtin_amdgcn_s_setprio(1);
    MF16(a0, bl[0]);
    __builtin_amdgcn_s_setprio(0);

    // ---- ph3: buf0 pass-l ks1 ----
    PH_TOP();
    LDB2(bl[1], 384, col1, 0);
    STAGE2(1, 3, kB);
    __builtin_amdgcn_s_setprio(1);
    MF16(a1, bl[1]);
    __builtin_amdgcn_s_setprio(0);

    // ---- ph4: buf1 pass-h ks0 ----
    asm volatile("s_waitcnt vmcnt(2)" ::: "memory");
    PH_TOP();
    LDA8(a0, col0, 1);
    LDB2(bh[0], 256, col0, 1);
    if (more) STAGE2(0, 0, kN);
    __builtin_amdgcn_s_setprio(1);
    MF16(a0, bh[0]);
    __builtin_amdgcn_s_setprio(0);

    // ---- ph5: buf1 pass-h ks1 ----
    if (more) { asm volatile("s_waitcnt vmcnt(2)" ::: "memory"); }
    else      { asm volatile("s_waitcnt vmcnt(0)" ::: "memory"); }
    PH_TOP();
    LDA8(a1, col1, 1);
    LDB2(bh[1], 256, col1, 1);
    if (more) STAGE2(0, 1, kN);
    __builtin_amdgcn_s_setprio(1);
    MF16(a1, bh[1]);
    __builtin_amdgcn_s_setprio(0);

    // ---- ph6: buf1 pass-l ks0 ----
    PH_TOP();
    LDB2(bl[0], 384, col0, 1);
    if (more) STAGE2(0, 2, kN);
    __builtin_amdgcn_s_setprio(1);
    MF16(a0, bl[0]);
    __builtin_amdgcn_s_setprio(0);

    // ---- ph7: buf1 pass-l ks1 ----
    PH_TOP();
    LDB2(bl[1], 384, col1, 1);
    if (more) STAGE2(0, 3, kN);
    __builtin_amdgcn_s_setprio(1);
    MF16(a1, bl[1]);
    __builtin_amdgcn_s_setprio(0);
  }

  // C/D layout: col = lane&15, row = (lane>>4)*4 + reg
  #pragma unroll
  for (int m2 = 0; m2 < 8; ++m2)
    #pragma unroll
    for (int n2 = 0; n2 < 2; ++n2) {
      int col = bn + wc + 16 * n2 + c15;
      #pragma unroll
      for (int r = 0; r < 4; ++r) {
        int row = bm + wr + 16 * m2 + quad * 4 + r;
        C[(size_t)row * N + col] = acc[m2][n2][r] * outscale;
      }
    }
#undef STAGE2
#undef LDA8
#undef LDB2
#undef MF16
#undef PH_TOP
}

// ---------------------------------------------------------------------------
// RMSNorm + RoPE on q,k of qkv[b,s,6144]; emits Q fp16 (single) and K hi/lo
// fp16, layout [b,h,s,d].
// ---------------------------------------------------------------------------
__global__ __launch_bounds__(256) void rmsrope_f16(
    const float* __restrict__ qkv, const float* __restrict__ cosb,
    const float* __restrict__ sinb, _Float16* __restrict__ Qg,
    _Float16* __restrict__ Khg, _Float16* __restrict__ Klg) {
  const int blk = blockIdx.x;           // b*SEQ + s
  const int b = blk >> 11, s = blk & (SEQ - 1);
  const int wave = threadIdx.x >> 6, lane = threadIdx.x & 63;
  const float* base = qkv + (size_t)blk * (3 * DIM);
  const float c  = cosb[s * HD + 2 * lane];
  const float sn = sinb[s * HD + 2 * lane];
  #pragma unroll
  for (int h = wave; h < NH; h += 4) {
    float2 q = *(const float2*)(base + h * HD + 2 * lane);
    float2 k = *(const float2*)(base + DIM + h * HD + 2 * lane);
    float ssq = q.x * q.x + q.y * q.y;
    float ssk = k.x * k.x + k.y * k.y;
    #pragma unroll
    for (int off = 32; off >= 1; off >>= 1) {
      ssq += __shfl_xor(ssq, off, 64);
      ssk += __shfl_xor(ssk, off, 64);
    }
    float rq = rsqrtf(ssq * (1.0f / HD) + EPS);
    float rk = rsqrtf(ssk * (1.0f / HD) + EPS);
    float q1 = q.x * rq, q2 = q.y * rq;
    float k1 = k.x * rk, k2 = k.y * rk;
    float qy1 = q1 * c - q2 * sn, qy2 = q1 * sn + q2 * c;
    float ky1 = k1 * c - k2 * sn, ky2 = k1 * sn + k2 * c;
    size_t o = ((size_t)(b * NH + h) * SEQ + s) * HD + 2 * lane;
    f16x2 qo, kh, kl;
    qo[0] = (_Float16)qy1; qo[1] = (_Float16)qy2;
    kh[0] = (_Float16)ky1; kl[0] = (_Float16)(ky1 - (float)kh[0]);
    kh[1] = (_Float16)ky2; kl[1] = (_Float16)(ky2 - (float)kh[1]);
    *(f16x2*)(Qg  + o) = qo;
    *(f16x2*)(Khg + o) = kh;
    *(f16x2*)(Klg + o) = kl;
  }
}

// ---------------------------------------------------------------------------
// V transpose: qkv v-slice [64 s][128 d] fp32 -> Vt [b,h,d,s] single fp16.
// ---------------------------------------------------------------------------
__global__ __launch_bounds__(256) void vtrans_f16(
    const float* __restrict__ qkv, _Float16* __restrict__ Vt) {
  __shared__ _Float16 L[64 * 132];
  const int t = threadIdx.x;
  const int s0 = blockIdx.x * 64, h = blockIdx.y, b = blockIdx.z;
  const float* src = qkv + ((size_t)(b * SEQ + s0)) * (3 * DIM) + 2 * DIM + h * HD;
  #pragma unroll
  for (int it = 0; it < 8; ++it) {
    int f = t + it * 256;
    int r = f >> 5, c4 = f & 31;
    float4 v = *(const float4*)(src + (size_t)r * (3 * DIM) + c4 * 4);
    f16x4 o;
    o[0] = (_Float16)v.x; o[1] = (_Float16)v.y;
    o[2] = (_Float16)v.z; o[3] = (_Float16)v.w;
    *(f16x4*)(&L[r * 132 + c4 * 4]) = o;
  }
  __syncthreads();
  const int d = t >> 1, sc = (t & 1) * 32;
  size_t dst = ((size_t)((b * NH + h) * HD + d)) * SEQ + s0 + sc;
  #pragma unroll
  for (int j = 0; j < 8; ++j) {
    f16x4 o;
    o[0] = L[(sc + 4 * j + 0) * 132 + d];
    o[1] = L[(sc + 4 * j + 1) * 132 + d];
    o[2] = L[(sc + 4 * j + 2) * 132 + d];
    o[3] = L[(sc + 4 * j + 3) * 132 + d];
    *(f16x4*)(Vt + dst + j * 4) = o;
  }
}

// ---------------------------------------------------------------------------
// fp16 MFMA flash attention, fixed-max softmax.
// Round-3 changes vs round-1: (a) double-buffered K/V/Vt staging with one
// barrier + counted drain per chunk (load latency covered by a full chunk of
// compute), (b) all 4 waves stage (6 loads each of 24), (c) XCD-aware block
// swizzle so a head's K/V stays in one XCD's L2 (16x reuse), (d) setprio
// around MFMA clusters.
// LDS f16 units: Kh[2] [0,8192)  Kl[2] [8192,16384)  Vt[2] [16384,24576)
// P [24576,29696) per wave [32][40].  Q staging reuses [0,16384).
// ---------------------------------------------------------------------------
#define QT 128
#define KC 32

__global__ __launch_bounds__(256, 2) void flash_f16(
    const _Float16* __restrict__ Qg, const _Float16* __restrict__ Khg,
    const _Float16* __restrict__ Klg, const _Float16* __restrict__ Vtg,
    _Float16* __restrict__ Og) {
  __shared__ __align__(16) _Float16 sm[29696];

  const int t = threadIdx.x, w = t >> 6, lane = t & 63;
  const int quad = lane >> 4, c15 = lane & 15;
  // XCD swizzle (xcd ~= bid%8): 64 blocks/XCD = 4 bh-groups x 16 q-chunks,
  // so each head's 1.5 MB K/V is reused 16x within one XCD's L2.
  const int bid = blockIdx.x;
  const int grp = (bid & 7) * 4 + ((bid >> 3) >> 4);   // 0..31 = b*NH+h
  const int qi  = (bid >> 3) & 15;
  const int bh = grp;
  const int hy = grp & (NH - 1), bz = grp >> 4;
  const int q0 = qi * QT;
  const int wr = w * 32;

  // ---- stage Q [128][128] f16 once; fragments -> registers ----
  {
    const _Float16* qsrc = Qg + ((size_t)bh * SEQ + q0) * HD;
    #pragma unroll
    for (int p = 0; p < 8; ++p) {
      int ci = p * 256 + t;
      int r = ci >> 4, c8 = (ci & 15) ^ (r & 15);
      __builtin_amdgcn_global_load_lds(
          (const __attribute__((address_space(1))) unsigned int*)(qsrc + (size_t)r * HD + c8 * 8),
          (__attribute__((address_space(3))) unsigned int*)(sm + ci * 8), 16, 0, 0);
    }
  }
  __syncthreads();
  f16x8 qf[2][4];  // [mf][ks]
  #pragma unroll
  for (int mf = 0; mf < 2; ++mf)
    #pragma unroll
    for (int ks = 0; ks < 4; ++ks) {
      int m = wr + mf * 16 + c15;
      int c8 = ks * 4 + quad;
      qf[mf][ks] = *(const f16x8*)(sm + (m * 16 + (c8 ^ (m & 15))) * 8);
    }
  // all waves' qf reads must retire before chunk staging overwrites [0,16384)
  asm volatile("s_waitcnt lgkmcnt(0)" ::: "memory");
  __builtin_amdgcn_sched_barrier(0);
  __syncthreads();

  float lrow[8];
  f32x4 oacc[2][8];
  #pragma unroll
  for (int i = 0; i < 8; ++i) lrow[i] = 0.f;
  #pragma unroll
  for (int mf = 0; mf < 2; ++mf)
    #pragma unroll
    for (int nf = 0; nf < 8; ++nf) oacc[mf][nf] = (f32x4){0.f, 0.f, 0.f, 0.f};

  const float sl = 0.12751744f;       // (1/sqrt(128)) * log2(e)
  const float M2 = 16.322231f;        // sqrt(128) * log2(e)  (|score|<=sqrt(128))
  _Float16* Pw = sm + 24576 + w * 1280;

  // 24 chunk loads (Kh 8, Kl 8, Vt 8) spread 6 per wave; tile wave-uniform.
#define STAGE_KV(buf, kk)                                                     \
  _Pragma("unroll")                                                           \
  for (int e = 0; e < 6; ++e) {                                               \
    int idx = w * 6 + e;                                                      \
    int tile = idx >> 3, p = idx & 7;                                         \
    int ci = p * 64 + lane;                                                   \
    if (tile < 2) {                                                           \
      int r = ci >> 4, c8 = (ci & 15) ^ (r & 15);                             \
      const _Float16* src = (tile == 0 ? Khg : Klg) +                         \
          ((size_t)bh * SEQ + (kk) + r) * HD + c8 * 8;                        \
      __builtin_amdgcn_global_load_lds(                                       \
          (const __attribute__((address_space(1))) unsigned int*)src,         \
          (__attribute__((address_space(3))) unsigned int*)                   \
              (sm + tile * 8192 + (buf) * 4096 + ci * 8), 16, 0, 0);          \
    } else {                                                                  \
      int d = ci >> 2, c8 = (ci & 3) ^ (d & 3);                               \
      const _Float16* src = Vtg + (size_t)bh * HD * SEQ + (size_t)d * SEQ     \
          + (kk) + c8 * 8;                                                    \
      __builtin_amdgcn_global_load_lds(                                       \
          (const __attribute__((address_space(1))) unsigned int*)src,         \
          (__attribute__((address_space(3))) unsigned int*)                   \
              (sm + 16384 + (buf) * 4096 + ci * 8), 16, 0, 0);                \
    }                                                                         \
  }

  STAGE_KV(0, 0)                       // prologue: chunk 0 -> buf0

  const int NC = SEQ / KC;             // 64
  for (int it = 0; it < NC; ++it) {
    const int cur = it & 1, cb0 = cur * 4096;
    // my chunk-`it` loads landed; barrier => everyone's landed AND everyone
    // is done reading buf 1-cur (their chunk it-1 compute retired).
    asm volatile("s_waitcnt vmcnt(0)" ::: "memory");
    __builtin_amdgcn_sched_barrier(0);
    __builtin_amdgcn_s_barrier();
    __builtin_amdgcn_sched_barrier(0);
    if (it + 1 < NC) { STAGE_KV(1 - cur, (it + 1) * KC) }

    // ---- S = Q K^T (2 passes: Kh then Kl) ----
    f32x4 accs[2][2] = {};
    #pragma unroll
    for (int nf = 0; nf < 2; ++nf) {
      f16x8 kh[4], kl[4];
      #pragma unroll
      for (int ks = 0; ks < 4; ++ks) {
        int n = nf * 16 + c15;
        int c8 = ks * 4 + quad;
        int slot = (n * 16 + (c8 ^ (n & 15))) * 8;
        kh[ks] = *(const f16x8*)(sm + cb0 + slot);
        kl[ks] = *(const f16x8*)(sm + 8192 + cb0 + slot);
      }
      __builtin_amdgcn_s_setprio(1);
      #pragma unroll
      for (int ks = 0; ks < 4; ++ks) {
        accs[0][nf] = MFMA_F16(qf[0][ks], kh[ks], accs[0][nf], 0, 0, 0);
        accs[1][nf] = MFMA_F16(qf[1][ks], kh[ks], accs[1][nf], 0, 0, 0);
      }
      #pragma unroll
      for (int ks = 0; ks < 4; ++ks) {
        accs[0][nf] = MFMA_F16(qf[0][ks], kl[ks], accs[0][nf], 0, 0, 0);
        accs[1][nf] = MFMA_F16(qf[1][ks], kl[ks], accs[1][nf], 0, 0, 0);
      }
      __builtin_amdgcn_s_setprio(0);
    }

    // ---- fixed-shift softmax weights (lane-local denominator) ----
    #pragma unroll
    for (int mf = 0; mf < 2; ++mf)
      #pragma unroll
      for (int reg = 0; reg < 4; ++reg) {
        float p0 = exp2f(fmaf(accs[mf][0][reg], sl, -M2));
        float p1 = exp2f(fmaf(accs[mf][1][reg], sl, -M2));
        lrow[mf * 4 + reg] += p0 + p1;
        int prow = mf * 16 + quad * 4 + reg;
        Pw[prow * 40 + c15]      = (_Float16)p0;
        Pw[prow * 40 + c15 + 16] = (_Float16)p1;
      }

    // ---- O += P V (single pass) ----
    f16x8 pa0 = *(const f16x8*)(Pw + (c15) * 40 + quad * 8);
    f16x8 pa1 = *(const f16x8*)(Pw + (16 + c15) * 40 + quad * 8);
    __builtin_amdgcn_s_setprio(1);
    #pragma unroll
    for (int nf = 0; nf < 8; ++nf) {
      int dd = nf * 16 + c15;
      int slot = (dd * 4 + (quad ^ (dd & 3))) * 8;
      f16x8 vv = *(const f16x8*)(sm + 16384 + cb0 + slot);
      oacc[0][nf] = MFMA_F16(pa0, vv, oacc[0][nf], 0, 0, 0);
      oacc[1][nf] = MFMA_F16(pa1, vv, oacc[1][nf], 0, 0, 0);
    }
    __builtin_amdgcn_s_setprio(0);
  }

  // ---- epilogue: denominator reduce + O write (single fp16) ----
  #pragma unroll
  for (int i = 0; i < 8; ++i) {
    float s = lrow[i];
    #pragma unroll
    for (int off = 8; off >= 1; off >>= 1) s += __shfl_xor(s, off, 64);
    lrow[i] = s;
  }
  #pragma unroll
  for (int mf = 0; mf < 2; ++mf)
    #pragma unroll
    for (int reg = 0; reg < 4; ++reg) {
      float inv = 1.0f / lrow[mf * 4 + reg];
      int row = q0 + wr + mf * 16 + quad * 4 + reg;
      size_t ob = ((size_t)bz * SEQ + row) * DIM + hy * HD + c15;
      #pragma unroll
      for (int nf = 0; nf < 8; ++nf)
        Og[ob + nf * 16] = (_Float16)(oacc[mf][nf][reg] * inv);
    }
#undef STAGE_KV
}

// ---------------------------------------------------------------------------
// Launch.  Workspace (<= 201 MB):
//   [0, 100663296)          qkv fp32 -> later O16 + Wph/Wpl
//   R = +100663296:
//     pre-gemm1 : x16 [R,+16.7M)  Wh [R+16.7M,+25.2M)  Wl [R+41.9M,+25.2M)
//     post-gemm1: Q16 [R) Kh [R+16.7M) Kl [R+33.6M) Vt [R+50.3M) (16.7M each)
//   O16 at ws[0,16.7M), Wph ws+16.7M, Wpl ws+25.2M (after qkv consumed).
// ---------------------------------------------------------------------------
extern "C" void kernel_launch(void* const* d_in, const int* in_sizes, int n_in,
                              void* d_out, int out_size, void* d_ws, size_t ws_size,
                              hipStream_t stream) {
  const float* x     = (const float*)d_in[0];
  const float* cosb  = (const float*)d_in[1];
  const float* sinb  = (const float*)d_in[2];
  const float* Wqkv  = (const float*)d_in[3];
  const float* Wproj = (const float*)d_in[4];
  float* out = (float*)d_out;

  char* ws = (char*)d_ws;
  float* qkv = (float*)ws;
  char* R = ws + 100663296;
  _Float16* x16 = (_Float16*)(R);
  _Float16* Wh  = (_Float16*)(R + 16777216);
  _Float16* Wl  = (_Float16*)(R + 41943040);
  _Float16* Q16 = (_Float16*)(R);
  _Float16* Kh  = (_Float16*)(R + 16777216);
  _Float16* Kl  = (_Float16*)(R + 33554432);
  _Float16* Vt  = (_Float16*)(R + 50331648);
  _Float16* O16 = (_Float16*)(ws);
  _Float16* Wph = (_Float16*)(ws + 16777216);
  _Float16* Wpl = (_Float16*)(ws + 25165824);

  cvt_f16  <<<8192,  256, 0, stream>>>(x, x16);
  split_f16s<<<12288, 256, 0, stream>>>(Wqkv, Wh, Wl);
  gemm_2p8<<<dim3(48, 16), 512, 0, stream>>>(x16, Wh, Wl, qkv, 4096, 6144, 2048, INV_WSCALE);
  rmsrope_f16<<<4096, 256, 0, stream>>>(qkv, cosb, sinb, Q16, Kh, Kl);
  vtrans_f16<<<dim3(32, NH, BATCH), 256, 0, stream>>>(qkv, Vt);
  split_f16s<<<4096, 256, 0, stream>>>(Wproj, Wph, Wpl);   // after qkv consumed
  flash_f16<<<512, 256, 0, stream>>>(Q16, Kh, Kl, Vt, O16);
  gemm_2p8<<<dim3(16, 16), 512, 0, stream>>>(O16, Wph, Wpl, out, 4096, 2048, 2048, INV_WSCALE);
}

// Round 4
// 521.022 us; speedup vs baseline: 1.2530x; 1.0154x over previous
//
#include <hip/hip_runtime.h>
#include <math.h>

// Problem constants
#define BATCH 2
#define SEQ   2048
#define DIM   2048
#define NH    16
#define HD    128
#define EPS   1e-6f

typedef _Float16 f16x8 __attribute__((ext_vector_type(8)));
typedef _Float16 f16x4 __attribute__((ext_vector_type(4)));
typedef _Float16 f16x2 __attribute__((ext_vector_type(2)));
typedef float    f32x4 __attribute__((ext_vector_type(4)));

#define MFMA_F16 __builtin_amdgcn_mfma_f32_16x16x32_f16

// W pre-scale: W*1024 keeps W_lo (~2^-12 * 0.02) in fp16 normal range.
#define WSCALE    1024.0f
#define INV_WSCALE 0.0009765625f

// ---------------------------------------------------------------------------
// fp32 -> fp16 (single), 4 el/thread
// ---------------------------------------------------------------------------
__global__ __launch_bounds__(256) void cvt_f16(
    const float* __restrict__ in, _Float16* __restrict__ out) {
  int i = blockIdx.x * 256 + threadIdx.x;
  float4 v = ((const float4*)in)[i];
  f16x4 o;
  o[0] = (_Float16)v.x; o[1] = (_Float16)v.y;
  o[2] = (_Float16)v.z; o[3] = (_Float16)v.w;
  ((f16x4*)out)[i] = o;
}

// ---------------------------------------------------------------------------
// fp32 -> (hi, lo) fp16 of value*1024 (weights)
// ---------------------------------------------------------------------------
__global__ __launch_bounds__(256) void split_f16s(
    const float* __restrict__ in, _Float16* __restrict__ hi,
    _Float16* __restrict__ lo) {
  int i = blockIdx.x * 256 + threadIdx.x;
  float4 v = ((const float4*)in)[i];
  f16x4 h, l;
  float s;
  s = v.x * WSCALE; h[0] = (_Float16)s; l[0] = (_Float16)(s - (float)h[0]);
  s = v.y * WSCALE; h[1] = (_Float16)s; l[1] = (_Float16)(s - (float)h[1]);
  s = v.z * WSCALE; h[2] = (_Float16)s; l[2] = (_Float16)(s - (float)h[2]);
  s = v.w * WSCALE; h[3] = (_Float16)s; l[3] = (_Float16)(s - (float)h[3]);
  ((f16x4*)hi)[i] = h;
  ((f16x4*)lo)[i] = l;
}

// ---------------------------------------------------------------------------
// 2-pass fp16 MFMA GEMM, 1-barrier-per-K-tile schedule.
//   C[M,N] = A[M,K] @ (Bh+Bl)[N,K]^T * outscale
// BM=256 BN=128 BK=64, 8 waves (2x4), per-wave 128x32.
// LDS: 2 buf x (A 256 + Bh 128 + Bl 128) rows x 64 f16 = 128 KiB (round-1
// proven layout + XOR-8 swizzle: zero bank conflicts).
// Round-4 change: merge the 8 sub-phase barriers into ONE barrier + ONE
// vmcnt(0) per K-tile.  Per K-tile per SIMD, ds_read time (~2314cy) and MFMA
// time (~2483cy) are balanced in SUM; the old per-phase barriers forced
// max() per phase (reads lumped 10/10/2/2) -> 3170cy.  Barrier-free flow
// inside the tile lets the 2 waves/SIMD skew (one reads while other MFMAs).
// Prefetch distance = 1 full tile, so vmcnt(0) is pre-drained.
// ---------------------------------------------------------------------------
#define BM8 256
#define BN8 128

__global__ __launch_bounds__(512, 2) void gemm_2p8(
    const _Float16* __restrict__ Ag, const _Float16* __restrict__ Bhg,
    const _Float16* __restrict__ Blg, float* __restrict__ C,
    int M, int N, int K, float outscale) {
  // stack rows: [0,256) = A, [256,384) = Bh, [384,512) = Bl; 64 f16 per row.
  __shared__ __align__(16) _Float16 smem[2][512][64];

  const int t = threadIdx.x;
  const int w = t >> 6, lane = t & 63;
  const int bm = blockIdx.y * BM8, bn = blockIdx.x * BN8;
  const int wr = (w >> 2) * 128;      // wave row offset (2 wave-rows)
  const int wc = (w & 3) * 32;        // wave col offset (4 wave-cols)
  const int quad = lane >> 4, c15 = lane & 15;

  const _Float16* baseA  = Ag  + (size_t)bm * K;
  const _Float16* baseBh = Bhg + (size_t)bn * K;
  const _Float16* baseBl = Blg + (size_t)bn * K;

  const int lrow = lane >> 3;
  const int lswz = ((lane & 7) ^ lrow) * 8;    // f16 units

  const int col0 = (((0 * 4) + quad) ^ (c15 & 7)) * 8;   // ks=0
  const int col1 = (((1 * 4) + quad) ^ (c15 & 7)) * 8;   // ks=1

  f32x4 acc[8][2] = {};
  f16x8 a0[8], a1[8], bh0[2], bh1[2], bl0[2], bl1[2];

  // wave-uniform staging of chunks q*16+2w, q*16+2w+1 into buffer `buf`
#define STAGE2(buf, q, kofs)                                                   \
  {                                                                            \
    _Pragma("unroll")                                                          \
    for (int e = 0; e < 2; ++e) {                                              \
      int c = (q) * 16 + 2 * w + e;                                            \
      int rl = c * 8 + lrow;                                                   \
      const _Float16* g;                                                       \
      if ((q) < 2)        g = baseA  + (size_t)rl * K;                         \
      else if ((q) == 2)  g = baseBh + (size_t)(rl - 256) * K;                 \
      else                g = baseBl + (size_t)(rl - 384) * K;                 \
      __builtin_amdgcn_global_load_lds(                                        \
          (const __attribute__((address_space(1))) unsigned int*)(g + (kofs) + lswz), \
          (__attribute__((address_space(3))) unsigned int*)(&smem[buf][(c) * 8][0]),  \
          16, 0, 0);                                                           \
    }                                                                          \
  }

#define STAGE_TILE(buf, kofs)                                                  \
  STAGE2(buf, 0, kofs) STAGE2(buf, 1, kofs)                                    \
  STAGE2(buf, 2, kofs) STAGE2(buf, 3, kofs)

#define LDA8(dst, colv, buf)                                                   \
  _Pragma("unroll")                                                            \
  for (int m2 = 0; m2 < 8; ++m2)                                               \
    dst[m2] = *(const f16x8*)(&smem[buf][wr + m2 * 16 + c15][colv]);

#define LDB2(dst, rbase, colv, buf)                                            \
  _Pragma("unroll")                                                            \
  for (int n2 = 0; n2 < 2; ++n2)                                               \
    dst[n2] = *(const f16x8*)(&smem[buf][(rbase) + wc + n2 * 16 + c15][colv]);

#define MF16(af, bf)                                                           \
  _Pragma("unroll")                                                            \
  for (int m2 = 0; m2 < 8; ++m2)                                               \
    _Pragma("unroll")                                                          \
    for (int n2 = 0; n2 < 2; ++n2)                                             \
      acc[m2][n2] = MFMA_F16(af[m2], bf[n2], acc[m2][n2], 0, 0, 0);

  STAGE_TILE(0, 0)                     // prologue: tile 0 -> buf0

  const int NT = K >> 6;               // 32 K-tiles
  for (int tt = 0; tt < NT; ++tt) {
    const int buf = tt & 1;
    // my tile-tt loads landed; barrier => everyone's landed AND everyone is
    // done reading buf 1-buf (their tile tt-1 ds_reads retired before their
    // barrier, since the MFMAs consumed them).
    asm volatile("s_waitcnt vmcnt(0)" ::: "memory");
    __builtin_amdgcn_sched_barrier(0);
    __builtin_amdgcn_s_barrier();
    __builtin_amdgcn_sched_barrier(0);
    if (tt + 1 < NT) { STAGE_TILE(1 - buf, (tt + 1) * 64) }
    __builtin_amdgcn_sched_barrier(0);  // stage issued before ds_reads

    // ---- half 1: ks0 cluster (12 reads, 32 MFMA) ----
    LDA8(a0, col0, buf);
    LDB2(bh0, 256, col0, buf);
    LDB2(bl0, 384, col0, buf);
    __builtin_amdgcn_s_setprio(1);
    MF16(a0, bh0);
    MF16(a0, bl0);
    __builtin_amdgcn_s_setprio(0);

    // ---- half 2: ks1 cluster (12 reads, 32 MFMA) ----
    LDA8(a1, col1, buf);
    LDB2(bh1, 256, col1, buf);
    LDB2(bl1, 384, col1, buf);
    __builtin_amdgcn_s_setprio(1);
    MF16(a1, bh1);
    MF16(a1, bl1);
    __builtin_amdgcn_s_setprio(0);
  }

  // C/D layout: col = lane&15, row = (lane>>4)*4 + reg
  #pragma unroll
  for (int m2 = 0; m2 < 8; ++m2)
    #pragma unroll
    for (int n2 = 0; n2 < 2; ++n2) {
      int col = bn + wc + 16 * n2 + c15;
      #pragma unroll
      for (int r = 0; r < 4; ++r) {
        int row = bm + wr + 16 * m2 + quad * 4 + r;
        C[(size_t)row * N + col] = acc[m2][n2][r] * outscale;
      }
    }
#undef STAGE2
#undef STAGE_TILE
#undef LDA8
#undef LDB2
#undef MF16
}

// ---------------------------------------------------------------------------
// RMSNorm + RoPE on q,k of qkv[b,s,6144]; emits Q fp16 (single) and K hi/lo
// fp16, layout [b,h,s,d].
// ---------------------------------------------------------------------------
__global__ __launch_bounds__(256) void rmsrope_f16(
    const float* __restrict__ qkv, const float* __restrict__ cosb,
    const float* __restrict__ sinb, _Float16* __restrict__ Qg,
    _Float16* __restrict__ Khg, _Float16* __restrict__ Klg) {
  const int blk = blockIdx.x;           // b*SEQ + s
  const int b = blk >> 11, s = blk & (SEQ - 1);
  const int wave = threadIdx.x >> 6, lane = threadIdx.x & 63;
  const float* base = qkv + (size_t)blk * (3 * DIM);
  const float c  = cosb[s * HD + 2 * lane];
  const float sn = sinb[s * HD + 2 * lane];
  #pragma unroll
  for (int h = wave; h < NH; h += 4) {
    float2 q = *(const float2*)(base + h * HD + 2 * lane);
    float2 k = *(const float2*)(base + DIM + h * HD + 2 * lane);
    float ssq = q.x * q.x + q.y * q.y;
    float ssk = k.x * k.x + k.y * k.y;
    #pragma unroll
    for (int off = 32; off >= 1; off >>= 1) {
      ssq += __shfl_xor(ssq, off, 64);
      ssk += __shfl_xor(ssk, off, 64);
    }
    float rq = rsqrtf(ssq * (1.0f / HD) + EPS);
    float rk = rsqrtf(ssk * (1.0f / HD) + EPS);
    float q1 = q.x * rq, q2 = q.y * rq;
    float k1 = k.x * rk, k2 = k.y * rk;
    float qy1 = q1 * c - q2 * sn, qy2 = q1 * sn + q2 * c;
    float ky1 = k1 * c - k2 * sn, ky2 = k1 * sn + k2 * c;
    size_t o = ((size_t)(b * NH + h) * SEQ + s) * HD + 2 * lane;
    f16x2 qo, kh, kl;
    qo[0] = (_Float16)qy1; qo[1] = (_Float16)qy2;
    kh[0] = (_Float16)ky1; kl[0] = (_Float16)(ky1 - (float)kh[0]);
    kh[1] = (_Float16)ky2; kl[1] = (_Float16)(ky2 - (float)kh[1]);
    *(f16x2*)(Qg  + o) = qo;
    *(f16x2*)(Khg + o) = kh;
    *(f16x2*)(Klg + o) = kl;
  }
}

// ---------------------------------------------------------------------------
// V transpose: qkv v-slice [64 s][128 d] fp32 -> Vt [b,h,d,s] single fp16.
// ---------------------------------------------------------------------------
__global__ __launch_bounds__(256) void vtrans_f16(
    const float* __restrict__ qkv, _Float16* __restrict__ Vt) {
  __shared__ _Float16 L[64 * 132];
  const int t = threadIdx.x;
  const int s0 = blockIdx.x * 64, h = blockIdx.y, b = blockIdx.z;
  const float* src = qkv + ((size_t)(b * SEQ + s0)) * (3 * DIM) + 2 * DIM + h * HD;
  #pragma unroll
  for (int it = 0; it < 8; ++it) {
    int f = t + it * 256;
    int r = f >> 5, c4 = f & 31;
    float4 v = *(const float4*)(src + (size_t)r * (3 * DIM) + c4 * 4);
    f16x4 o;
    o[0] = (_Float16)v.x; o[1] = (_Float16)v.y;
    o[2] = (_Float16)v.z; o[3] = (_Float16)v.w;
    *(f16x4*)(&L[r * 132 + c4 * 4]) = o;
  }
  __syncthreads();
  const int d = t >> 1, sc = (t & 1) * 32;
  size_t dst = ((size_t)((b * NH + h) * HD + d)) * SEQ + s0 + sc;
  #pragma unroll
  for (int j = 0; j < 8; ++j) {
    f16x4 o;
    o[0] = L[(sc + 4 * j + 0) * 132 + d];
    o[1] = L[(sc + 4 * j + 1) * 132 + d];
    o[2] = L[(sc + 4 * j + 2) * 132 + d];
    o[3] = L[(sc + 4 * j + 3) * 132 + d];
    *(f16x4*)(Vt + dst + j * 4) = o;
  }
}

// ---------------------------------------------------------------------------
// fp16 MFMA flash attention, fixed-max softmax (round-3 state, unchanged:
// double-buffered K/V/Vt staging, all-wave staging, XCD swizzle, setprio).
// LDS f16 units: Kh[2] [0,8192)  Kl[2] [8192,16384)  Vt[2] [16384,24576)
// P [24576,29696) per wave [32][40].  Q staging reuses [0,16384).
// ---------------------------------------------------------------------------
#define QT 128
#define KC 32

__global__ __launch_bounds__(256, 2) void flash_f16(
    const _Float16* __restrict__ Qg, const _Float16* __restrict__ Khg,
    const _Float16* __restrict__ Klg, const _Float16* __restrict__ Vtg,
    _Float16* __restrict__ Og) {
  __shared__ __align__(16) _Float16 sm[29696];

  const int t = threadIdx.x, w = t >> 6, lane = t & 63;
  const int quad = lane >> 4, c15 = lane & 15;
  // XCD swizzle: 64 blocks/XCD = 4 bh-groups x 16 q-chunks, so each head's
  // 1.5 MB K/V is reused 16x within one XCD's L2.
  const int bid = blockIdx.x;
  const int grp = (bid & 7) * 4 + ((bid >> 3) >> 4);   // 0..31 = b*NH+h
  const int qi  = (bid >> 3) & 15;
  const int bh = grp;
  const int hy = grp & (NH - 1), bz = grp >> 4;
  const int q0 = qi * QT;
  const int wr = w * 32;

  // ---- stage Q [128][128] f16 once; fragments -> registers ----
  {
    const _Float16* qsrc = Qg + ((size_t)bh * SEQ + q0) * HD;
    #pragma unroll
    for (int p = 0; p < 8; ++p) {
      int ci = p * 256 + t;
      int r = ci >> 4, c8 = (ci & 15) ^ (r & 15);
      __builtin_amdgcn_global_load_lds(
          (const __attribute__((address_space(1))) unsigned int*)(qsrc + (size_t)r * HD + c8 * 8),
          (__attribute__((address_space(3))) unsigned int*)(sm + ci * 8), 16, 0, 0);
    }
  }
  __syncthreads();
  f16x8 qf[2][4];  // [mf][ks]
  #pragma unroll
  for (int mf = 0; mf < 2; ++mf)
    #pragma unroll
    for (int ks = 0; ks < 4; ++ks) {
      int m = wr + mf * 16 + c15;
      int c8 = ks * 4 + quad;
      qf[mf][ks] = *(const f16x8*)(sm + (m * 16 + (c8 ^ (m & 15))) * 8);
    }
  // all waves' qf reads must retire before chunk staging overwrites [0,16384)
  asm volatile("s_waitcnt lgkmcnt(0)" ::: "memory");
  __builtin_amdgcn_sched_barrier(0);
  __syncthreads();

  float lrow[8];
  f32x4 oacc[2][8];
  #pragma unroll
  for (int i = 0; i < 8; ++i) lrow[i] = 0.f;
  #pragma unroll
  for (int mf = 0; mf < 2; ++mf)
    #pragma unroll
    for (int nf = 0; nf < 8; ++nf) oacc[mf][nf] = (f32x4){0.f, 0.f, 0.f, 0.f};

  const float sl = 0.12751744f;       // (1/sqrt(128)) * log2(e)
  const float M2 = 16.322231f;        // sqrt(128) * log2(e)  (|score|<=sqrt(128))
  _Float16* Pw = sm + 24576 + w * 1280;

  // 24 chunk loads (Kh 8, Kl 8, Vt 8) spread 6 per wave; tile wave-uniform.
#define STAGE_KV(buf, kk)                                                     \
  _Pragma("unroll")                                                           \
  for (int e = 0; e < 6; ++e) {                                               \
    int idx = w * 6 + e;                                                      \
    int tile = idx >> 3, p = idx & 7;                                         \
    int ci = p * 64 + lane;                                                   \
    if (tile < 2) {                                                           \
      int r = ci >> 4, c8 = (ci & 15) ^ (r & 15);                             \
      const _Float16* src = (tile == 0 ? Khg : Klg) +                         \
          ((size_t)bh * SEQ + (kk) + r) * HD + c8 * 8;                        \
      __builtin_amdgcn_global_load_lds(                                       \
          (const __attribute__((address_space(1))) unsigned int*)src,         \
          (__attribute__((address_space(3))) unsigned int*)                   \
              (sm + tile * 8192 + (buf) * 4096 + ci * 8), 16, 0, 0);          \
    } else {                                                                  \
      int d = ci >> 2, c8 = (ci & 3) ^ (d & 3);                               \
      const _Float16* src = Vtg + (size_t)bh * HD * SEQ + (size_t)d * SEQ     \
          + (kk) + c8 * 8;                                                    \
      __builtin_amdgcn_global_load_lds(                                       \
          (const __attribute__((address_space(1))) unsigned int*)src,         \
          (__attribute__((address_space(3))) unsigned int*)                   \
              (sm + 16384 + (buf) * 4096 + ci * 8), 16, 0, 0);                \
    }                                                                         \
  }

  STAGE_KV(0, 0)                       // prologue: chunk 0 -> buf0

  const int NC = SEQ / KC;             // 64
  for (int it = 0; it < NC; ++it) {
    const int cur = it & 1, cb0 = cur * 4096;
    asm volatile("s_waitcnt vmcnt(0)" ::: "memory");
    __builtin_amdgcn_sched_barrier(0);
    __builtin_amdgcn_s_barrier();
    __builtin_amdgcn_sched_barrier(0);
    if (it + 1 < NC) { STAGE_KV(1 - cur, (it + 1) * KC) }

    // ---- S = Q K^T (2 passes: Kh then Kl) ----
    f32x4 accs[2][2] = {};
    #pragma unroll
    for (int nf = 0; nf < 2; ++nf) {
      f16x8 kh[4], kl[4];
      #pragma unroll
      for (int ks = 0; ks < 4; ++ks) {
        int n = nf * 16 + c15;
        int c8 = ks * 4 + quad;
        int slot = (n * 16 + (c8 ^ (n & 15))) * 8;
        kh[ks] = *(const f16x8*)(sm + cb0 + slot);
        kl[ks] = *(const f16x8*)(sm + 8192 + cb0 + slot);
      }
      __builtin_amdgcn_s_setprio(1);
      #pragma unroll
      for (int ks = 0; ks < 4; ++ks) {
        accs[0][nf] = MFMA_F16(qf[0][ks], kh[ks], accs[0][nf], 0, 0, 0);
        accs[1][nf] = MFMA_F16(qf[1][ks], kh[ks], accs[1][nf], 0, 0, 0);
      }
      #pragma unroll
      for (int ks = 0; ks < 4; ++ks) {
        accs[0][nf] = MFMA_F16(qf[0][ks], kl[ks], accs[0][nf], 0, 0, 0);
        accs[1][nf] = MFMA_F16(qf[1][ks], kl[ks], accs[1][nf], 0, 0, 0);
      }
      __builtin_amdgcn_s_setprio(0);
    }

    // ---- fixed-shift softmax weights (lane-local denominator) ----
    #pragma unroll
    for (int mf = 0; mf < 2; ++mf)
      #pragma unroll
      for (int reg = 0; reg < 4; ++reg) {
        float p0 = exp2f(fmaf(accs[mf][0][reg], sl, -M2));
        float p1 = exp2f(fmaf(accs[mf][1][reg], sl, -M2));
        lrow[mf * 4 + reg] += p0 + p1;
        int prow = mf * 16 + quad * 4 + reg;
        Pw[prow * 40 + c15]      = (_Float16)p0;
        Pw[prow * 40 + c15 + 16] = (_Float16)p1;
      }

    // ---- O += P V (single pass) ----
    f16x8 pa0 = *(const f16x8*)(Pw + (c15) * 40 + quad * 8);
    f16x8 pa1 = *(const f16x8*)(Pw + (16 + c15) * 40 + quad * 8);
    __builtin_amdgcn_s_setprio(1);
    #pragma unroll
    for (int nf = 0; nf < 8; ++nf) {
      int dd = nf * 16 + c15;
      int slot = (dd * 4 + (quad ^ (dd & 3))) * 8;
      f16x8 vv = *(const f16x8*)(sm + 16384 + cb0 + slot);
      oacc[0][nf] = MFMA_F16(pa0, vv, oacc[0][nf], 0, 0, 0);
      oacc[1][nf] = MFMA_F16(pa1, vv, oacc[1][nf], 0, 0, 0);
    }
    __builtin_amdgcn_s_setprio(0);
  }

  // ---- epilogue: denominator reduce + O write (single fp16) ----
  #pragma unroll
  for (int i = 0; i < 8; ++i) {
    float s = lrow[i];
    #pragma unroll
    for (int off = 8; off >= 1; off >>= 1) s += __shfl_xor(s, off, 64);
    lrow[i] = s;
  }
  #pragma unroll
  for (int mf = 0; mf < 2; ++mf)
    #pragma unroll
    for (int reg = 0; reg < 4; ++reg) {
      float inv = 1.0f / lrow[mf * 4 + reg];
      int row = q0 + wr + mf * 16 + quad * 4 + reg;
      size_t ob = ((size_t)bz * SEQ + row) * DIM + hy * HD + c15;
      #pragma unroll
      for (int nf = 0; nf < 8; ++nf)
        Og[ob + nf * 16] = (_Float16)(oacc[mf][nf][reg] * inv);
    }
#undef STAGE_KV
}

// ---------------------------------------------------------------------------
// Launch.  Workspace (<= 201 MB):
//   [0, 100663296)          qkv fp32 -> later O16 + Wph/Wpl
//   R = +100663296:
//     pre-gemm1 : x16 [R,+16.7M)  Wh [R+16.7M,+25.2M)  Wl [R+41.9M,+25.2M)
//     post-gemm1: Q16 [R) Kh [R+16.7M) Kl [R+33.6M) Vt [R+50.3M) (16.7M each)
//   O16 at ws[0,16.7M), Wph ws+16.7M, Wpl ws+25.2M (after qkv consumed).
// ---------------------------------------------------------------------------
extern "C" void kernel_launch(void* const* d_in, const int* in_sizes, int n_in,
                              void* d_out, int out_size, void* d_ws, size_t ws_size,
                              hipStream_t stream) {
  const float* x     = (const float*)d_in[0];
  const float* cosb  = (const float*)d_in[1];
  const float* sinb  = (const float*)d_in[2];
  const float* Wqkv  = (const float*)d_in[3];
  const float* Wproj = (const float*)d_in[4];
  float* out = (float*)d_out;

  char* ws = (char*)d_ws;
  float* qkv = (float*)ws;
  char* R = ws + 100663296;
  _Float16* x16 = (_Float16*)(R);
  _Float16* Wh  = (_Float16*)(R + 16777216);
  _Float16* Wl  = (_Float16*)(R + 41943040);
  _Float16* Q16 = (_Float16*)(R);
  _Float16* Kh  = (_Float16*)(R + 16777216);
  _Float16* Kl  = (_Float16*)(R + 33554432);
  _Float16* Vt  = (_Float16*)(R + 50331648);
  _Float16* O16 = (_Float16*)(ws);
  _Float16* Wph = (_Float16*)(ws + 16777216);
  _Float16* Wpl = (_Float16*)(ws + 25165824);

  cvt_f16  <<<8192,  256, 0, stream>>>(x, x16);
  split_f16s<<<12288, 256, 0, stream>>>(Wqkv, Wh, Wl);
  gemm_2p8<<<dim3(48, 16), 512, 0, stream>>>(x16, Wh, Wl, qkv, 4096, 6144, 2048, INV_WSCALE);
  rmsrope_f16<<<4096, 256, 0, stream>>>(qkv, cosb, sinb, Q16, Kh, Kl);
  vtrans_f16<<<dim3(32, NH, BATCH), 256, 0, stream>>>(qkv, Vt);
  split_f16s<<<4096, 256, 0, stream>>>(Wproj, Wph, Wpl);   // after qkv consumed
  flash_f16<<<512, 256, 0, stream>>>(Q16, Kh, Kl, Vt, O16);
  gemm_2p8<<<dim3(16, 16), 512, 0, stream>>>(O16, Wph, Wpl, out, 4096, 2048, 2048, INV_WSCALE);
}

// Round 5
// 519.571 us; speedup vs baseline: 1.2565x; 1.0028x over previous
//
#include <hip/hip_runtime.h>
#include <math.h>

// Problem constants
#define BATCH 2
#define SEQ   2048
#define DIM   2048
#define NH    16
#define HD    128
#define EPS   1e-6f

typedef _Float16 f16x8 __attribute__((ext_vector_type(8)));
typedef _Float16 f16x4 __attribute__((ext_vector_type(4)));
typedef _Float16 f16x2 __attribute__((ext_vector_type(2)));
typedef float    f32x4 __attribute__((ext_vector_type(4)));

#define MFMA_F16 __builtin_amdgcn_mfma_f32_16x16x32_f16

// W pre-scale: W*1024 keeps W_lo (~2^-12 * 0.02) in fp16 normal range.
#define WSCALE    1024.0f
#define INV_WSCALE 0.0009765625f

// ---------------------------------------------------------------------------
// fp32 -> fp16 (single), 4 el/thread
// ---------------------------------------------------------------------------
__global__ __launch_bounds__(256) void cvt_f16(
    const float* __restrict__ in, _Float16* __restrict__ out) {
  int i = blockIdx.x * 256 + threadIdx.x;
  float4 v = ((const float4*)in)[i];
  f16x4 o;
  o[0] = (_Float16)v.x; o[1] = (_Float16)v.y;
  o[2] = (_Float16)v.z; o[3] = (_Float16)v.w;
  ((f16x4*)out)[i] = o;
}

// ---------------------------------------------------------------------------
// fp32 -> (hi, lo) fp16 of value*1024 (weights)
// ---------------------------------------------------------------------------
__global__ __launch_bounds__(256) void split_f16s(
    const float* __restrict__ in, _Float16* __restrict__ hi,
    _Float16* __restrict__ lo) {
  int i = blockIdx.x * 256 + threadIdx.x;
  float4 v = ((const float4*)in)[i];
  f16x4 h, l;
  float s;
  s = v.x * WSCALE; h[0] = (_Float16)s; l[0] = (_Float16)(s - (float)h[0]);
  s = v.y * WSCALE; h[1] = (_Float16)s; l[1] = (_Float16)(s - (float)h[1]);
  s = v.z * WSCALE; h[2] = (_Float16)s; l[2] = (_Float16)(s - (float)h[2]);
  s = v.w * WSCALE; h[3] = (_Float16)s; l[3] = (_Float16)(s - (float)h[3]);
  ((f16x4*)hi)[i] = h;
  ((f16x4*)lo)[i] = l;
}

// ---------------------------------------------------------------------------
// 2-pass fp16 MFMA GEMM, 1 barrier/K-tile + intra-tile read/MFMA pipeline.
//   C[M,N] = A[M,K] @ (Bh+Bl)[N,K]^T * outscale
// BM=256 BN=128 BK=64, 8 waves (2x4), per-wave 128x32.
// LDS: 2 buf x (A 256 + Bh 128 + Bl 128) rows x 64 f16 = 128 KiB; XOR-8
// swizzle (zero bank conflicts, round-1 proven).
// Round-5 change: round-4 counters showed tile wall = MFMA time + LDS-read
// time IN SERIES (4775cy = 2483 + 2304): waves march in lockstep, LDS port
// idles during MFMA and vice versa.  Now ALL 24 ds_read_b128 issue up front
// in consumption order; 64 MFMA run as 4 clusters of 16 fenced by
// sched_barrier(0).  Compiler auto-inserts COUNTED lgkmcnt per cluster
// (16/12/4/0) -> ~2/3 of read port time hides under MFMA.
// ---------------------------------------------------------------------------
#define BM8 256
#define BN8 128

__global__ __launch_bounds__(512, 2) void gemm_2p8(
    const _Float16* __restrict__ Ag, const _Float16* __restrict__ Bhg,
    const _Float16* __restrict__ Blg, float* __restrict__ C,
    int M, int N, int K, float outscale) {
  // stack rows: [0,256) = A, [256,384) = Bh, [384,512) = Bl; 64 f16 per row.
  __shared__ __align__(16) _Float16 smem[2][512][64];

  const int t = threadIdx.x;
  const int w = t >> 6, lane = t & 63;
  const int bm = blockIdx.y * BM8, bn = blockIdx.x * BN8;
  const int wr = (w >> 2) * 128;      // wave row offset (2 wave-rows)
  const int wc = (w & 3) * 32;        // wave col offset (4 wave-cols)
  const int quad = lane >> 4, c15 = lane & 15;

  const _Float16* baseA  = Ag  + (size_t)bm * K;
  const _Float16* baseBh = Bhg + (size_t)bn * K;
  const _Float16* baseBl = Blg + (size_t)bn * K;

  const int lrow = lane >> 3;
  const int lswz = ((lane & 7) ^ lrow) * 8;    // f16 units

  const int col0 = (((0 * 4) + quad) ^ (c15 & 7)) * 8;   // ks=0
  const int col1 = (((1 * 4) + quad) ^ (c15 & 7)) * 8;   // ks=1

  f32x4 acc[8][2] = {};
  f16x8 a0[8], a1[8], bh0[2], bh1[2], bl0[2], bl1[2];

  // wave-uniform staging of chunks q*16+2w, q*16+2w+1 into buffer `buf`
#define STAGE2(buf, q, kofs)                                                   \
  {                                                                            \
    _Pragma("unroll")                                                          \
    for (int e = 0; e < 2; ++e) {                                              \
      int c = (q) * 16 + 2 * w + e;                                            \
      int rl = c * 8 + lrow;                                                   \
      const _Float16* g;                                                       \
      if ((q) < 2)        g = baseA  + (size_t)rl * K;                         \
      else if ((q) == 2)  g = baseBh + (size_t)(rl - 256) * K;                 \
      else                g = baseBl + (size_t)(rl - 384) * K;                 \
      __builtin_amdgcn_global_load_lds(                                        \
          (const __attribute__((address_space(1))) unsigned int*)(g + (kofs) + lswz), \
          (__attribute__((address_space(3))) unsigned int*)(&smem[buf][(c) * 8][0]),  \
          16, 0, 0);                                                           \
    }                                                                          \
  }

#define STAGE_TILE(buf, kofs)                                                  \
  STAGE2(buf, 0, kofs) STAGE2(buf, 1, kofs)                                    \
  STAGE2(buf, 2, kofs) STAGE2(buf, 3, kofs)

#define LDA4(dst, base, colv, buf)                                             \
  _Pragma("unroll")                                                            \
  for (int m2 = 0; m2 < 4; ++m2)                                               \
    dst[(base) + m2] =                                                         \
        *(const f16x8*)(&smem[buf][wr + ((base) + m2) * 16 + c15][colv]);

#define LDB2(dst, rbase, colv, buf)                                            \
  _Pragma("unroll")                                                            \
  for (int n2 = 0; n2 < 2; ++n2)                                               \
    dst[n2] = *(const f16x8*)(&smem[buf][(rbase) + wc + n2 * 16 + c15][colv]);

  // 8-MFMA cluster: rows [base, base+4) x 2 cols with one B pair
#define MH(af, base, bf)                                                       \
  _Pragma("unroll")                                                            \
  for (int m2 = 0; m2 < 4; ++m2)                                               \
    _Pragma("unroll")                                                          \
    for (int n2 = 0; n2 < 2; ++n2)                                             \
      acc[(base) + m2][n2] =                                                   \
          MFMA_F16(af[(base) + m2], bf[n2], acc[(base) + m2][n2], 0, 0, 0);

#define SB() __builtin_amdgcn_sched_barrier(0);

  STAGE_TILE(0, 0)                     // prologue: tile 0 -> buf0

  const int NT = K >> 6;               // 32 K-tiles
  for (int tt = 0; tt < NT; ++tt) {
    const int buf = tt & 1;
    // my tile-tt loads landed; barrier => everyone's landed AND everyone is
    // done reading buf 1-buf.
    asm volatile("s_waitcnt vmcnt(0)" ::: "memory");
    SB();
    __builtin_amdgcn_s_barrier();
    SB();
    if (tt + 1 < NT) { STAGE_TILE(1 - buf, (tt + 1) * 64) }
    SB();

    // ---- issue ALL 24 fragment reads, in consumption order ----
    LDA4(a0, 0, col0, buf);            // reads  1-4
    LDB2(bh0, 256, col0, buf);         // reads  5-6
    LDB2(bl0, 384, col0, buf);         // reads  7-8
    LDA4(a0, 4, col0, buf);            // reads  9-12
    LDA4(a1, 0, col1, buf);            // reads 13-16
    LDB2(bh1, 256, col1, buf);         // reads 17-18
    LDB2(bl1, 384, col1, buf);         // reads 19-20
    LDA4(a1, 4, col1, buf);            // reads 21-24
    SB();

    // ---- 4 x 16-MFMA clusters; auto-counted lgkmcnt 16/12/4/0 ----
    __builtin_amdgcn_s_setprio(1);
    MH(a0, 0, bh0); MH(a0, 0, bl0);    // needs reads 1-8
    __builtin_amdgcn_s_setprio(0);
    SB();
    __builtin_amdgcn_s_setprio(1);
    MH(a0, 4, bh0); MH(a0, 4, bl0);    // needs reads 9-12
    __builtin_amdgcn_s_setprio(0);
    SB();
    __builtin_amdgcn_s_setprio(1);
    MH(a1, 0, bh1); MH(a1, 0, bl1);    // needs reads 13-20
    __builtin_amdgcn_s_setprio(0);
    SB();
    __builtin_amdgcn_s_setprio(1);
    MH(a1, 4, bh1); MH(a1, 4, bl1);    // needs reads 21-24
    __builtin_amdgcn_s_setprio(0);
  }

  // C/D layout: col = lane&15, row = (lane>>4)*4 + reg
  #pragma unroll
  for (int m2 = 0; m2 < 8; ++m2)
    #pragma unroll
    for (int n2 = 0; n2 < 2; ++n2) {
      int col = bn + wc + 16 * n2 + c15;
      #pragma unroll
      for (int r = 0; r < 4; ++r) {
        int row = bm + wr + 16 * m2 + quad * 4 + r;
        C[(size_t)row * N + col] = acc[m2][n2][r] * outscale;
      }
    }
#undef STAGE2
#undef STAGE_TILE
#undef LDA4
#undef LDB2
#undef MH
#undef SB
}

// ---------------------------------------------------------------------------
// RMSNorm + RoPE on q,k of qkv[b,s,6144]; emits Q fp16 (single) and K hi/lo
// fp16, layout [b,h,s,d].
// ---------------------------------------------------------------------------
__global__ __launch_bounds__(256) void rmsrope_f16(
    const float* __restrict__ qkv, const float* __restrict__ cosb,
    const float* __restrict__ sinb, _Float16* __restrict__ Qg,
    _Float16* __restrict__ Khg, _Float16* __restrict__ Klg) {
  const int blk = blockIdx.x;           // b*SEQ + s
  const int b = blk >> 11, s = blk & (SEQ - 1);
  const int wave = threadIdx.x >> 6, lane = threadIdx.x & 63;
  const float* base = qkv + (size_t)blk * (3 * DIM);
  const float c  = cosb[s * HD + 2 * lane];
  const float sn = sinb[s * HD + 2 * lane];
  #pragma unroll
  for (int h = wave; h < NH; h += 4) {
    float2 q = *(const float2*)(base + h * HD + 2 * lane);
    float2 k = *(const float2*)(base + DIM + h * HD + 2 * lane);
    float ssq = q.x * q.x + q.y * q.y;
    float ssk = k.x * k.x + k.y * k.y;
    #pragma unroll
    for (int off = 32; off >= 1; off >>= 1) {
      ssq += __shfl_xor(ssq, off, 64);
      ssk += __shfl_xor(ssk, off, 64);
    }
    float rq = rsqrtf(ssq * (1.0f / HD) + EPS);
    float rk = rsqrtf(ssk * (1.0f / HD) + EPS);
    float q1 = q.x * rq, q2 = q.y * rq;
    float k1 = k.x * rk, k2 = k.y * rk;
    float qy1 = q1 * c - q2 * sn, qy2 = q1 * sn + q2 * c;
    float ky1 = k1 * c - k2 * sn, ky2 = k1 * sn + k2 * c;
    size_t o = ((size_t)(b * NH + h) * SEQ + s) * HD + 2 * lane;
    f16x2 qo, kh, kl;
    qo[0] = (_Float16)qy1; qo[1] = (_Float16)qy2;
    kh[0] = (_Float16)ky1; kl[0] = (_Float16)(ky1 - (float)kh[0]);
    kh[1] = (_Float16)ky2; kl[1] = (_Float16)(ky2 - (float)kh[1]);
    *(f16x2*)(Qg  + o) = qo;
    *(f16x2*)(Khg + o) = kh;
    *(f16x2*)(Klg + o) = kl;
  }
}

// ---------------------------------------------------------------------------
// V transpose: qkv v-slice [64 s][128 d] fp32 -> Vt [b,h,d,s] single fp16.
// ---------------------------------------------------------------------------
__global__ __launch_bounds__(256) void vtrans_f16(
    const float* __restrict__ qkv, _Float16* __restrict__ Vt) {
  __shared__ _Float16 L[64 * 132];
  const int t = threadIdx.x;
  const int s0 = blockIdx.x * 64, h = blockIdx.y, b = blockIdx.z;
  const float* src = qkv + ((size_t)(b * SEQ + s0)) * (3 * DIM) + 2 * DIM + h * HD;
  #pragma unroll
  for (int it = 0; it < 8; ++it) {
    int f = t + it * 256;
    int r = f >> 5, c4 = f & 31;
    float4 v = *(const float4*)(src + (size_t)r * (3 * DIM) + c4 * 4);
    f16x4 o;
    o[0] = (_Float16)v.x; o[1] = (_Float16)v.y;
    o[2] = (_Float16)v.z; o[3] = (_Float16)v.w;
    *(f16x4*)(&L[r * 132 + c4 * 4]) = o;
  }
  __syncthreads();
  const int d = t >> 1, sc = (t & 1) * 32;
  size_t dst = ((size_t)((b * NH + h) * HD + d)) * SEQ + s0 + sc;
  #pragma unroll
  for (int j = 0; j < 8; ++j) {
    f16x4 o;
    o[0] = L[(sc + 4 * j + 0) * 132 + d];
    o[1] = L[(sc + 4 * j + 1) * 132 + d];
    o[2] = L[(sc + 4 * j + 2) * 132 + d];
    o[3] = L[(sc + 4 * j + 3) * 132 + d];
    *(f16x4*)(Vt + dst + j * 4) = o;
  }
}

// ---------------------------------------------------------------------------
// fp16 MFMA flash attention, fixed-max softmax (round-3 state, unchanged:
// double-buffered K/V/Vt staging, all-wave staging, XCD swizzle, setprio).
// LDS f16 units: Kh[2] [0,8192)  Kl[2] [8192,16384)  Vt[2] [16384,24576)
// P [24576,29696) per wave [32][40].  Q staging reuses [0,16384).
// ---------------------------------------------------------------------------
#define QT 128
#define KC 32

__global__ __launch_bounds__(256, 2) void flash_f16(
    const _Float16* __restrict__ Qg, const _Float16* __restrict__ Khg,
    const _Float16* __restrict__ Klg, const _Float16* __restrict__ Vtg,
    _Float16* __restrict__ Og) {
  __shared__ __align__(16) _Float16 sm[29696];

  const int t = threadIdx.x, w = t >> 6, lane = t & 63;
  const int quad = lane >> 4, c15 = lane & 15;
  // XCD swizzle: 64 blocks/XCD = 4 bh-groups x 16 q-chunks, so each head's
  // 1.5 MB K/V is reused 16x within one XCD's L2.
  const int bid = blockIdx.x;
  const int grp = (bid & 7) * 4 + ((bid >> 3) >> 4);   // 0..31 = b*NH+h
  const int qi  = (bid >> 3) & 15;
  const int bh = grp;
  const int hy = grp & (NH - 1), bz = grp >> 4;
  const int q0 = qi * QT;
  const int wr = w * 32;

  // ---- stage Q [128][128] f16 once; fragments -> registers ----
  {
    const _Float16* qsrc = Qg + ((size_t)bh * SEQ + q0) * HD;
    #pragma unroll
    for (int p = 0; p < 8; ++p) {
      int ci = p * 256 + t;
      int r = ci >> 4, c8 = (ci & 15) ^ (r & 15);
      __builtin_amdgcn_global_load_lds(
          (const __attribute__((address_space(1))) unsigned int*)(qsrc + (size_t)r * HD + c8 * 8),
          (__attribute__((address_space(3))) unsigned int*)(sm + ci * 8), 16, 0, 0);
    }
  }
  __syncthreads();
  f16x8 qf[2][4];  // [mf][ks]
  #pragma unroll
  for (int mf = 0; mf < 2; ++mf)
    #pragma unroll
    for (int ks = 0; ks < 4; ++ks) {
      int m = wr + mf * 16 + c15;
      int c8 = ks * 4 + quad;
      qf[mf][ks] = *(const f16x8*)(sm + (m * 16 + (c8 ^ (m & 15))) * 8);
    }
  // all waves' qf reads must retire before chunk staging overwrites [0,16384)
  asm volatile("s_waitcnt lgkmcnt(0)" ::: "memory");
  __builtin_amdgcn_sched_barrier(0);
  __syncthreads();

  float lrow[8];
  f32x4 oacc[2][8];
  #pragma unroll
  for (int i = 0; i < 8; ++i) lrow[i] = 0.f;
  #pragma unroll
  for (int mf = 0; mf < 2; ++mf)
    #pragma unroll
    for (int nf = 0; nf < 8; ++nf) oacc[mf][nf] = (f32x4){0.f, 0.f, 0.f, 0.f};

  const float sl = 0.12751744f;       // (1/sqrt(128)) * log2(e)
  const float M2 = 16.322231f;        // sqrt(128) * log2(e)  (|score|<=sqrt(128))
  _Float16* Pw = sm + 24576 + w * 1280;

  // 24 chunk loads (Kh 8, Kl 8, Vt 8) spread 6 per wave; tile wave-uniform.
#define STAGE_KV(buf, kk)                                                     \
  _Pragma("unroll")                                                           \
  for (int e = 0; e < 6; ++e) {                                               \
    int idx = w * 6 + e;                                                      \
    int tile = idx >> 3, p = idx & 7;                                         \
    int ci = p * 64 + lane;                                                   \
    if (tile < 2) {                                                           \
      int r = ci >> 4, c8 = (ci & 15) ^ (r & 15);                             \
      const _Float16* src = (tile == 0 ? Khg : Klg) +                         \
          ((size_t)bh * SEQ + (kk) + r) * HD + c8 * 8;                        \
      __builtin_amdgcn_global_load_lds(                                       \
          (const __attribute__((address_space(1))) unsigned int*)src,         \
          (__attribute__((address_space(3))) unsigned int*)                   \
              (sm + tile * 8192 + (buf) * 4096 + ci * 8), 16, 0, 0);          \
    } else {                                                                  \
      int d = ci >> 2, c8 = (ci & 3) ^ (d & 3);                               \
      const _Float16* src = Vtg + (size_t)bh * HD * SEQ + (size_t)d * SEQ     \
          + (kk) + c8 * 8;                                                    \
      __builtin_amdgcn_global_load_lds(                                       \
          (const __attribute__((address_space(1))) unsigned int*)src,         \
          (__attribute__((address_space(3))) unsigned int*)                   \
              (sm + 16384 + (buf) * 4096 + ci * 8), 16, 0, 0);                \
    }                                                                         \
  }

  STAGE_KV(0, 0)                       // prologue: chunk 0 -> buf0

  const int NC = SEQ / KC;             // 64
  for (int it = 0; it < NC; ++it) {
    const int cur = it & 1, cb0 = cur * 4096;
    asm volatile("s_waitcnt vmcnt(0)" ::: "memory");
    __builtin_amdgcn_sched_barrier(0);
    __builtin_amdgcn_s_barrier();
    __builtin_amdgcn_sched_barrier(0);
    if (it + 1 < NC) { STAGE_KV(1 - cur, (it + 1) * KC) }

    // ---- S = Q K^T (2 passes: Kh then Kl) ----
    f32x4 accs[2][2] = {};
    #pragma unroll
    for (int nf = 0; nf < 2; ++nf) {
      f16x8 kh[4], kl[4];
      #pragma unroll
      for (int ks = 0; ks < 4; ++ks) {
        int n = nf * 16 + c15;
        int c8 = ks * 4 + quad;
        int slot = (n * 16 + (c8 ^ (n & 15))) * 8;
        kh[ks] = *(const f16x8*)(sm + cb0 + slot);
        kl[ks] = *(const f16x8*)(sm + 8192 + cb0 + slot);
      }
      __builtin_amdgcn_s_setprio(1);
      #pragma unroll
      for (int ks = 0; ks < 4; ++ks) {
        accs[0][nf] = MFMA_F16(qf[0][ks], kh[ks], accs[0][nf], 0, 0, 0);
        accs[1][nf] = MFMA_F16(qf[1][ks], kh[ks], accs[1][nf], 0, 0, 0);
      }
      #pragma unroll
      for (int ks = 0; ks < 4; ++ks) {
        accs[0][nf] = MFMA_F16(qf[0][ks], kl[ks], accs[0][nf], 0, 0, 0);
        accs[1][nf] = MFMA_F16(qf[1][ks], kl[ks], accs[1][nf], 0, 0, 0);
      }
      __builtin_amdgcn_s_setprio(0);
    }

    // ---- fixed-shift softmax weights (lane-local denominator) ----
    #pragma unroll
    for (int mf = 0; mf < 2; ++mf)
      #pragma unroll
      for (int reg = 0; reg < 4; ++reg) {
        float p0 = exp2f(fmaf(accs[mf][0][reg], sl, -M2));
        float p1 = exp2f(fmaf(accs[mf][1][reg], sl, -M2));
        lrow[mf * 4 + reg] += p0 + p1;
        int prow = mf * 16 + quad * 4 + reg;
        Pw[prow * 40 + c15]      = (_Float16)p0;
        Pw[prow * 40 + c15 + 16] = (_Float16)p1;
      }

    // ---- O += P V (single pass) ----
    f16x8 pa0 = *(const f16x8*)(Pw + (c15) * 40 + quad * 8);
    f16x8 pa1 = *(const f16x8*)(Pw + (16 + c15) * 40 + quad * 8);
    __builtin_amdgcn_s_setprio(1);
    #pragma unroll
    for (int nf = 0; nf < 8; ++nf) {
      int dd = nf * 16 + c15;
      int slot = (dd * 4 + (quad ^ (dd & 3))) * 8;
      f16x8 vv = *(const f16x8*)(sm + 16384 + cb0 + slot);
      oacc[0][nf] = MFMA_F16(pa0, vv, oacc[0][nf], 0, 0, 0);
      oacc[1][nf] = MFMA_F16(pa1, vv, oacc[1][nf], 0, 0, 0);
    }
    __builtin_amdgcn_s_setprio(0);
  }

  // ---- epilogue: denominator reduce + O write (single fp16) ----
  #pragma unroll
  for (int i = 0; i < 8; ++i) {
    float s = lrow[i];
    #pragma unroll
    for (int off = 8; off >= 1; off >>= 1) s += __shfl_xor(s, off, 64);
    lrow[i] = s;
  }
  #pragma unroll
  for (int mf = 0; mf < 2; ++mf)
    #pragma unroll
    for (int reg = 0; reg < 4; ++reg) {
      float inv = 1.0f / lrow[mf * 4 + reg];
      int row = q0 + wr + mf * 16 + quad * 4 + reg;
      size_t ob = ((size_t)bz * SEQ + row) * DIM + hy * HD + c15;
      #pragma unroll
      for (int nf = 0; nf < 8; ++nf)
        Og[ob + nf * 16] = (_Float16)(oacc[mf][nf][reg] * inv);
    }
#undef STAGE_KV
}

// ---------------------------------------------------------------------------
// Launch.  Workspace (<= 201 MB):
//   [0, 100663296)          qkv fp32 -> later O16 + Wph/Wpl
//   R = +100663296:
//     pre-gemm1 : x16 [R,+16.7M)  Wh [R+16.7M,+25.2M)  Wl [R+41.9M,+25.2M)
//     post-gemm1: Q16 [R) Kh [R+16.7M) Kl [R+33.6M) Vt [R+50.3M) (16.7M each)
//   O16 at ws[0,16.7M), Wph ws+16.7M, Wpl ws+25.2M (after qkv consumed).
// ---------------------------------------------------------------------------
extern "C" void kernel_launch(void* const* d_in, const int* in_sizes, int n_in,
                              void* d_out, int out_size, void* d_ws, size_t ws_size,
                              hipStream_t stream) {
  const float* x     = (const float*)d_in[0];
  const float* cosb  = (const float*)d_in[1];
  const float* sinb  = (const float*)d_in[2];
  const float* Wqkv  = (const float*)d_in[3];
  const float* Wproj = (const float*)d_in[4];
  float* out = (float*)d_out;

  char* ws = (char*)d_ws;
  float* qkv = (float*)ws;
  char* R = ws + 100663296;
  _Float16* x16 = (_Float16*)(R);
  _Float16* Wh  = (_Float16*)(R + 16777216);
  _Float16* Wl  = (_Float16*)(R + 41943040);
  _Float16* Q16 = (_Float16*)(R);
  _Float16* Kh  = (_Float16*)(R + 16777216);
  _Float16* Kl  = (_Float16*)(R + 33554432);
  _Float16* Vt  = (_Float16*)(R + 50331648);
  _Float16* O16 = (_Float16*)(ws);
  _Float16* Wph = (_Float16*)(ws + 16777216);
  _Float16* Wpl = (_Float16*)(ws + 25165824);

  cvt_f16  <<<8192,  256, 0, stream>>>(x, x16);
  split_f16s<<<12288, 256, 0, stream>>>(Wqkv, Wh, Wl);
  gemm_2p8<<<dim3(48, 16), 512, 0, stream>>>(x16, Wh, Wl, qkv, 4096, 6144, 2048, INV_WSCALE);
  rmsrope_f16<<<4096, 256, 0, stream>>>(qkv, cosb, sinb, Q16, Kh, Kl);
  vtrans_f16<<<dim3(32, NH, BATCH), 256, 0, stream>>>(qkv, Vt);
  split_f16s<<<4096, 256, 0, stream>>>(Wproj, Wph, Wpl);   // after qkv consumed
  flash_f16<<<512, 256, 0, stream>>>(Q16, Kh, Kl, Vt, O16);
  gemm_2p8<<<dim3(16, 16), 512, 0, stream>>>(O16, Wph, Wpl, out, 4096, 2048, 2048, INV_WSCALE);
}

// Round 7
// 427.185 us; speedup vs baseline: 1.5283x; 1.2163x over previous
//
#include <hip/hip_runtime.h>
#include <math.h>

// Problem constants
#define BATCH 2
#define SEQ   2048
#define DIM   2048
#define NH    16
#define HD    128
#define EPS   1e-6f

typedef _Float16 f16x8 __attribute__((ext_vector_type(8)));
typedef _Float16 f16x4 __attribute__((ext_vector_type(4)));
typedef _Float16 f16x2 __attribute__((ext_vector_type(2)));
typedef float    f32x4 __attribute__((ext_vector_type(4)));

#define MFMA_F16 __builtin_amdgcn_mfma_f32_16x16x32_f16

// ---------------------------------------------------------------------------
// fp32 -> fp16 (single), 4 el/thread.  Used for x AND for W (round-6: W is
// single fp16 — the hi/lo split's lo-term contributes ~2.2e-4 absmax vs the
// 4.88e-4 floor set by fp16 activation quantization; dropped).
// ---------------------------------------------------------------------------
__global__ __launch_bounds__(256) void cvt_f16(
    const float* __restrict__ in, _Float16* __restrict__ out) {
  int i = blockIdx.x * 256 + threadIdx.x;
  float4 v = ((const float4*)in)[i];
  f16x4 o;
  o[0] = (_Float16)v.x; o[1] = (_Float16)v.y;
  o[2] = (_Float16)v.z; o[3] = (_Float16)v.w;
  ((f16x4*)out)[i] = o;
}

// ---------------------------------------------------------------------------
// Single-pass fp16 MFMA GEMM:  C[M,N] = A[M,K] @ B[N,K]^T
// BM=256 BN=128 BK=64, 8 waves (2x4), per-wave 128x32.
// LDS: 2 buf x (A 256 + B 128) rows x 64 f16 = 96 KiB; XOR-8 swizzle on
// 128B rows (round-1 proven geometry: zero bank conflicts).
// Schedule: 1 vmcnt(0)+barrier per K-tile, stage-next-early, all 20
// fragment reads up front, 2 MFMA clusters (schedules tie per r1/r4/r5 —
// wall = LDS-port time + MFMA time summed; this round shrinks the terms:
// 32 MFMA (was 64) + 20 reads (was 24) per tile).
// ---------------------------------------------------------------------------
#define BM8 256
#define BN8 128

__global__ __launch_bounds__(512, 2) void gemm_1p(
    const _Float16* __restrict__ Ag, const _Float16* __restrict__ Bg,
    float* __restrict__ C, int M, int N, int K) {
  // stack rows: [0,256) = A, [256,384) = B; 64 f16 per row.
  __shared__ __align__(16) _Float16 smem[2][384][64];

  const int t = threadIdx.x;
  const int w = t >> 6, lane = t & 63;
  const int bm = blockIdx.y * BM8, bn = blockIdx.x * BN8;
  const int wr = (w >> 2) * 128;      // wave row offset (2 wave-rows)
  const int wc = (w & 3) * 32;        // wave col offset (4 wave-cols)
  const int quad = lane >> 4, c15 = lane & 15;

  const _Float16* baseA = Ag + (size_t)bm * K;
  const _Float16* baseB = Bg + (size_t)bn * K;

  const int lrow = lane >> 3;
  const int lswz = ((lane & 7) ^ lrow) * 8;    // f16 units

  const int col0 = (((0 * 4) + quad) ^ (c15 & 7)) * 8;   // ks=0
  const int col1 = (((1 * 4) + quad) ^ (c15 & 7)) * 8;   // ks=1

  f32x4 acc[8][2] = {};
  f16x8 a0[8], a1[8], b0[2], b1[2];

  // 48 staging chunks (A 32, B 16), 6 per wave; chunk = 8 rows x 128B.
#define STAGE_TILE(buf, kofs)                                                  \
  {                                                                            \
    _Pragma("unroll")                                                          \
    for (int e = 0; e < 6; ++e) {                                              \
      int c = w * 6 + e;                                                       \
      int rl = c * 8 + lrow;                                                   \
      const _Float16* g = (rl < 256) ? (baseA + (size_t)rl * K)                \
                                     : (baseB + (size_t)(rl - 256) * K);       \
      __builtin_amdgcn_global_load_lds(                                        \
          (const __attribute__((address_space(1))) unsigned int*)(g + (kofs) + lswz), \
          (__attribute__((address_space(3))) unsigned int*)(&smem[buf][c * 8][0]),    \
          16, 0, 0);                                                           \
    }                                                                          \
  }

#define LDA8(dst, colv, buf)                                                   \
  _Pragma("unroll")                                                            \
  for (int m2 = 0; m2 < 8; ++m2)                                               \
    dst[m2] = *(const f16x8*)(&smem[buf][wr + m2 * 16 + c15][colv]);

#define LDB2(dst, colv, buf)                                                   \
  _Pragma("unroll")                                                            \
  for (int n2 = 0; n2 < 2; ++n2)                                               \
    dst[n2] = *(const f16x8*)(&smem[buf][256 + wc + n2 * 16 + c15][colv]);

#define MF16(af, bf)                                                           \
  _Pragma("unroll")                                                            \
  for (int m2 = 0; m2 < 8; ++m2)                                               \
    _Pragma("unroll")                                                          \
    for (int n2 = 0; n2 < 2; ++n2)                                             \
      acc[m2][n2] = MFMA_F16(af[m2], bf[n2], acc[m2][n2], 0, 0, 0);

#define SB() __builtin_amdgcn_sched_barrier(0);

  STAGE_TILE(0, 0)                     // prologue: tile 0 -> buf0

  const int NT = K >> 6;               // 32 K-tiles
  for (int tt = 0; tt < NT; ++tt) {
    const int buf = tt & 1;
    // my tile-tt loads landed; barrier => everyone's landed AND everyone is
    // done reading buf 1-buf.
    asm volatile("s_waitcnt vmcnt(0)" ::: "memory");
    SB();
    __builtin_amdgcn_s_barrier();
    SB();
    if (tt + 1 < NT) { STAGE_TILE(1 - buf, (tt + 1) * 64) }
    SB();

    // ---- all 20 fragment reads, consumption order ----
    LDA8(a0, col0, buf);
    LDB2(b0, col0, buf);
    LDA8(a1, col1, buf);
    LDB2(b1, col1, buf);
    SB();

    // ---- 2 x 16-MFMA clusters ----
    __builtin_amdgcn_s_setprio(1);
    MF16(a0, b0);
    __builtin_amdgcn_s_setprio(0);
    SB();
    __builtin_amdgcn_s_setprio(1);
    MF16(a1, b1);
    __builtin_amdgcn_s_setprio(0);
  }

  // C/D layout: col = lane&15, row = (lane>>4)*4 + reg
  #pragma unroll
  for (int m2 = 0; m2 < 8; ++m2)
    #pragma unroll
    for (int n2 = 0; n2 < 2; ++n2) {
      int col = bn + wc + 16 * n2 + c15;
      #pragma unroll
      for (int r = 0; r < 4; ++r) {
        int row = bm + wr + 16 * m2 + quad * 4 + r;
        C[(size_t)row * N + col] = acc[m2][n2][r];
      }
    }
#undef STAGE_TILE
#undef LDA8
#undef LDB2
#undef MF16
#undef SB
}

// ---------------------------------------------------------------------------
// RMSNorm + RoPE on q,k of qkv[b,s,6144]; emits Q fp16 (single) and K hi/lo
// fp16, layout [b,h,s,d].  (Flash keeps the K 2-pass; score precision
// untouched this round.)
// ---------------------------------------------------------------------------
__global__ __launch_bounds__(256) void rmsrope_f16(
    const float* __restrict__ qkv, const float* __restrict__ cosb,
    const float* __restrict__ sinb, _Float16* __restrict__ Qg,
    _Float16* __restrict__ Khg, _Float16* __restrict__ Klg) {
  const int blk = blockIdx.x;           // b*SEQ + s
  const int b = blk >> 11, s = blk & (SEQ - 1);
  const int wave = threadIdx.x >> 6, lane = threadIdx.x & 63;
  const float* base = qkv + (size_t)blk * (3 * DIM);
  const float c  = cosb[s * HD + 2 * lane];
  const float sn = sinb[s * HD + 2 * lane];
  #pragma unroll
  for (int h = wave; h < NH; h += 4) {
    float2 q = *(const float2*)(base + h * HD + 2 * lane);
    float2 k = *(const float2*)(base + DIM + h * HD + 2 * lane);
    float ssq = q.x * q.x + q.y * q.y;
    float ssk = k.x * k.x + k.y * k.y;
    #pragma unroll
    for (int off = 32; off >= 1; off >>= 1) {
      ssq += __shfl_xor(ssq, off, 64);
      ssk += __shfl_xor(ssk, off, 64);
    }
    float rq = rsqrtf(ssq * (1.0f / HD) + EPS);
    float rk = rsqrtf(ssk * (1.0f / HD) + EPS);
    float q1 = q.x * rq, q2 = q.y * rq;
    float k1 = k.x * rk, k2 = k.y * rk;
    float qy1 = q1 * c - q2 * sn, qy2 = q1 * sn + q2 * c;
    float ky1 = k1 * c - k2 * sn, ky2 = k1 * sn + k2 * c;
    size_t o = ((size_t)(b * NH + h) * SEQ + s) * HD + 2 * lane;
    f16x2 qo, kh, kl;
    qo[0] = (_Float16)qy1; qo[1] = (_Float16)qy2;
    kh[0] = (_Float16)ky1; kl[0] = (_Float16)(ky1 - (float)kh[0]);
    kh[1] = (_Float16)ky2; kl[1] = (_Float16)(ky2 - (float)kh[1]);
    *(f16x2*)(Qg  + o) = qo;
    *(f16x2*)(Khg + o) = kh;
    *(f16x2*)(Klg + o) = kl;
  }
}

// ---------------------------------------------------------------------------
// V transpose: qkv v-slice [64 s][128 d] fp32 -> Vt [b,h,d,s] single fp16.
// ---------------------------------------------------------------------------
__global__ __launch_bounds__(256) void vtrans_f16(
    const float* __restrict__ qkv, _Float16* __restrict__ Vt) {
  __shared__ _Float16 L[64 * 132];
  const int t = threadIdx.x;
  const int s0 = blockIdx.x * 64, h = blockIdx.y, b = blockIdx.z;
  const float* src = qkv + ((size_t)(b * SEQ + s0)) * (3 * DIM) + 2 * DIM + h * HD;
  #pragma unroll
  for (int it = 0; it < 8; ++it) {
    int f = t + it * 256;
    int r = f >> 5, c4 = f & 31;
    float4 v = *(const float4*)(src + (size_t)r * (3 * DIM) + c4 * 4);
    f16x4 o;
    o[0] = (_Float16)v.x; o[1] = (_Float16)v.y;
    o[2] = (_Float16)v.z; o[3] = (_Float16)v.w;
    *(f16x4*)(&L[r * 132 + c4 * 4]) = o;
  }
  __syncthreads();
  const int d = t >> 1, sc = (t & 1) * 32;
  size_t dst = ((size_t)((b * NH + h) * HD + d)) * SEQ + s0 + sc;
  #pragma unroll
  for (int j = 0; j < 8; ++j) {
    f16x4 o;
    o[0] = L[(sc + 4 * j + 0) * 132 + d];
    o[1] = L[(sc + 4 * j + 1) * 132 + d];
    o[2] = L[(sc + 4 * j + 2) * 132 + d];
    o[3] = L[(sc + 4 * j + 3) * 132 + d];
    *(f16x4*)(Vt + dst + j * 4) = o;
  }
}

// ---------------------------------------------------------------------------
// fp16 MFMA flash attention, fixed-max softmax (round-3 state, unchanged:
// double-buffered K/V/Vt staging, all-wave staging, XCD swizzle, setprio).
// LDS f16 units: Kh[2] [0,8192)  Kl[2] [8192,16384)  Vt[2] [16384,24576)
// P [24576,29696) per wave [32][40].  Q staging reuses [0,16384).
// ---------------------------------------------------------------------------
#define QT 128
#define KC 32

__global__ __launch_bounds__(256, 2) void flash_f16(
    const _Float16* __restrict__ Qg, const _Float16* __restrict__ Khg,
    const _Float16* __restrict__ Klg, const _Float16* __restrict__ Vtg,
    _Float16* __restrict__ Og) {
  __shared__ __align__(16) _Float16 sm[29696];

  const int t = threadIdx.x, w = t >> 6, lane = t & 63;
  const int quad = lane >> 4, c15 = lane & 15;
  // XCD swizzle: 64 blocks/XCD = 4 bh-groups x 16 q-chunks, so each head's
  // 1.5 MB K/V is reused 16x within one XCD's L2.
  const int bid = blockIdx.x;
  const int grp = (bid & 7) * 4 + ((bid >> 3) >> 4);   // 0..31 = b*NH+h
  const int qi  = (bid >> 3) & 15;
  const int bh = grp;
  const int hy = grp & (NH - 1), bz = grp >> 4;
  const int q0 = qi * QT;
  const int wr = w * 32;

  // ---- stage Q [128][128] f16 once; fragments -> registers ----
  {
    const _Float16* qsrc = Qg + ((size_t)bh * SEQ + q0) * HD;
    #pragma unroll
    for (int p = 0; p < 8; ++p) {
      int ci = p * 256 + t;
      int r = ci >> 4, c8 = (ci & 15) ^ (r & 15);
      __builtin_amdgcn_global_load_lds(
          (const __attribute__((address_space(1))) unsigned int*)(qsrc + (size_t)r * HD + c8 * 8),
          (__attribute__((address_space(3))) unsigned int*)(sm + ci * 8), 16, 0, 0);
    }
  }
  __syncthreads();
  f16x8 qf[2][4];  // [mf][ks]
  #pragma unroll
  for (int mf = 0; mf < 2; ++mf)
    #pragma unroll
    for (int ks = 0; ks < 4; ++ks) {
      int m = wr + mf * 16 + c15;
      int c8 = ks * 4 + quad;
      qf[mf][ks] = *(const f16x8*)(sm + (m * 16 + (c8 ^ (m & 15))) * 8);
    }
  // all waves' qf reads must retire before chunk staging overwrites [0,16384)
  asm volatile("s_waitcnt lgkmcnt(0)" ::: "memory");
  __builtin_amdgcn_sched_barrier(0);
  __syncthreads();

  float lrow[8];
  f32x4 oacc[2][8];
  #pragma unroll
  for (int i = 0; i < 8; ++i) lrow[i] = 0.f;
  #pragma unroll
  for (int mf = 0; mf < 2; ++mf)
    #pragma unroll
    for (int nf = 0; nf < 8; ++nf) oacc[mf][nf] = (f32x4){0.f, 0.f, 0.f, 0.f};

  const float sl = 0.12751744f;       // (1/sqrt(128)) * log2(e)
  const float M2 = 16.322231f;        // sqrt(128) * log2(e)  (|score|<=sqrt(128))
  _Float16* Pw = sm + 24576 + w * 1280;

  // 24 chunk loads (Kh 8, Kl 8, Vt 8) spread 6 per wave; tile wave-uniform.
#define STAGE_KV(buf, kk)                                                     \
  _Pragma("unroll")                                                           \
  for (int e = 0; e < 6; ++e) {                                               \
    int idx = w * 6 + e;                                                      \
    int tile = idx >> 3, p = idx & 7;                                         \
    int ci = p * 64 + lane;                                                   \
    if (tile < 2) {                                                           \
      int r = ci >> 4, c8 = (ci & 15) ^ (r & 15);                             \
      const _Float16* src = (tile == 0 ? Khg : Klg) +                         \
          ((size_t)bh * SEQ + (kk) + r) * HD + c8 * 8;                        \
      __builtin_amdgcn_global_load_lds(                                       \
          (const __attribute__((address_space(1))) unsigned int*)src,         \
          (__attribute__((address_space(3))) unsigned int*)                   \
              (sm + tile * 8192 + (buf) * 4096 + ci * 8), 16, 0, 0);          \
    } else {                                                                  \
      int d = ci >> 2, c8 = (ci & 3) ^ (d & 3);                               \
      const _Float16* src = Vtg + (size_t)bh * HD * SEQ + (size_t)d * SEQ     \
          + (kk) + c8 * 8;                                                    \
      __builtin_amdgcn_global_load_lds(                                       \
          (const __attribute__((address_space(1))) unsigned int*)src,         \
          (__attribute__((address_space(3))) unsigned int*)                   \
              (sm + 16384 + (buf) * 4096 + ci * 8), 16, 0, 0);                \
    }                                                                         \
  }

  STAGE_KV(0, 0)                       // prologue: chunk 0 -> buf0

  const int NC = SEQ / KC;             // 64
  for (int it = 0; it < NC; ++it) {
    const int cur = it & 1, cb0 = cur * 4096;
    asm volatile("s_waitcnt vmcnt(0)" ::: "memory");
    __builtin_amdgcn_sched_barrier(0);
    __builtin_amdgcn_s_barrier();
    __builtin_amdgcn_sched_barrier(0);
    if (it + 1 < NC) { STAGE_KV(1 - cur, (it + 1) * KC) }

    // ---- S = Q K^T (2 passes: Kh then Kl) ----
    f32x4 accs[2][2] = {};
    #pragma unroll
    for (int nf = 0; nf < 2; ++nf) {
      f16x8 kh[4], kl[4];
      #pragma unroll
      for (int ks = 0; ks < 4; ++ks) {
        int n = nf * 16 + c15;
        int c8 = ks * 4 + quad;
        int slot = (n * 16 + (c8 ^ (n & 15))) * 8;
        kh[ks] = *(const f16x8*)(sm + cb0 + slot);
        kl[ks] = *(const f16x8*)(sm + 8192 + cb0 + slot);
      }
      __builtin_amdgcn_s_setprio(1);
      #pragma unroll
      for (int ks = 0; ks < 4; ++ks) {
        accs[0][nf] = MFMA_F16(qf[0][ks], kh[ks], accs[0][nf], 0, 0, 0);
        accs[1][nf] = MFMA_F16(qf[1][ks], kh[ks], accs[1][nf], 0, 0, 0);
      }
      #pragma unroll
      for (int ks = 0; ks < 4; ++ks) {
        accs[0][nf] = MFMA_F16(qf[0][ks], kl[ks], accs[0][nf], 0, 0, 0);
        accs[1][nf] = MFMA_F16(qf[1][ks], kl[ks], accs[1][nf], 0, 0, 0);
      }
      __builtin_amdgcn_s_setprio(0);
    }

    // ---- fixed-shift softmax weights (lane-local denominator) ----
    #pragma unroll
    for (int mf = 0; mf < 2; ++mf)
      #pragma unroll
      for (int reg = 0; reg < 4; ++reg) {
        float p0 = exp2f(fmaf(accs[mf][0][reg], sl, -M2));
        float p1 = exp2f(fmaf(accs[mf][1][reg], sl, -M2));
        lrow[mf * 4 + reg] += p0 + p1;
        int prow = mf * 16 + quad * 4 + reg;
        Pw[prow * 40 + c15]      = (_Float16)p0;
        Pw[prow * 40 + c15 + 16] = (_Float16)p1;
      }

    // ---- O += P V (single pass) ----
    f16x8 pa0 = *(const f16x8*)(Pw + (c15) * 40 + quad * 8);
    f16x8 pa1 = *(const f16x8*)(Pw + (16 + c15) * 40 + quad * 8);
    __builtin_amdgcn_s_setprio(1);
    #pragma unroll
    for (int nf = 0; nf < 8; ++nf) {
      int dd = nf * 16 + c15;
      int slot = (dd * 4 + (quad ^ (dd & 3))) * 8;
      f16x8 vv = *(const f16x8*)(sm + 16384 + cb0 + slot);
      oacc[0][nf] = MFMA_F16(pa0, vv, oacc[0][nf], 0, 0, 0);
      oacc[1][nf] = MFMA_F16(pa1, vv, oacc[1][nf], 0, 0, 0);
    }
    __builtin_amdgcn_s_setprio(0);
  }

  // ---- epilogue: denominator reduce + O write (single fp16) ----
  #pragma unroll
  for (int i = 0; i < 8; ++i) {
    float s = lrow[i];
    #pragma unroll
    for (int off = 8; off >= 1; off >>= 1) s += __shfl_xor(s, off, 64);
    lrow[i] = s;
  }
  #pragma unroll
  for (int mf = 0; mf < 2; ++mf)
    #pragma unroll
    for (int reg = 0; reg < 4; ++reg) {
      float inv = 1.0f / lrow[mf * 4 + reg];
      int row = q0 + wr + mf * 16 + quad * 4 + reg;
      size_t ob = ((size_t)bz * SEQ + row) * DIM + hy * HD + c15;
      #pragma unroll
      for (int nf = 0; nf < 8; ++nf)
        Og[ob + nf * 16] = (_Float16)(oacc[mf][nf][reg] * inv);
    }
#undef STAGE_KV
}

// ---------------------------------------------------------------------------
// Launch.  Workspace (<= 201 MB):
//   [0, 100663296)          qkv fp32 -> later O16 + Wph
//   R = +100663296:
//     pre-gemm1 : x16 [R,+16.7M)  Wh [R+16.7M,+25.2M)
//     post-gemm1: Q16 [R) Kh [R+16.7M) Kl [R+33.6M) Vt [R+50.3M) (16.7M each)
//   O16 at ws[0,16.7M), Wph ws+16.7M (after qkv consumed).
// ---------------------------------------------------------------------------
extern "C" void kernel_launch(void* const* d_in, const int* in_sizes, int n_in,
                              void* d_out, int out_size, void* d_ws, size_t ws_size,
                              hipStream_t stream) {
  const float* x     = (const float*)d_in[0];
  const float* cosb  = (const float*)d_in[1];
  const float* sinb  = (const float*)d_in[2];
  const float* Wqkv  = (const float*)d_in[3];
  const float* Wproj = (const float*)d_in[4];
  float* out = (float*)d_out;

  char* ws = (char*)d_ws;
  float* qkv = (float*)ws;
  char* R = ws + 100663296;
  _Float16* x16 = (_Float16*)(R);
  _Float16* Wh  = (_Float16*)(R + 16777216);
  _Float16* Q16 = (_Float16*)(R);
  _Float16* Kh  = (_Float16*)(R + 16777216);
  _Float16* Kl  = (_Float16*)(R + 33554432);
  _Float16* Vt  = (_Float16*)(R + 50331648);
  _Float16* O16 = (_Float16*)(ws);
  _Float16* Wph = (_Float16*)(ws + 16777216);

  cvt_f16<<<8192,  256, 0, stream>>>(x, x16);
  cvt_f16<<<12288, 256, 0, stream>>>(Wqkv, Wh);
  gemm_1p<<<dim3(48, 16), 512, 0, stream>>>(x16, Wh, qkv, 4096, 6144, 2048);
  rmsrope_f16<<<4096, 256, 0, stream>>>(qkv, cosb, sinb, Q16, Kh, Kl);
  vtrans_f16<<<dim3(32, NH, BATCH), 256, 0, stream>>>(qkv, Vt);
  cvt_f16<<<4096, 256, 0, stream>>>(Wproj, Wph);   // after qkv consumed
  flash_f16<<<512, 256, 0, stream>>>(Q16, Kh, Kl, Vt, O16);
  gemm_1p<<<dim3(16, 16), 512, 0, stream>>>(O16, Wph, out, 4096, 2048, 2048);
}

// Round 8
// 423.069 us; speedup vs baseline: 1.5432x; 1.0097x over previous
//
#include <hip/hip_runtime.h>
#include <math.h>

// Problem constants
#define BATCH 2
#define SEQ   2048
#define DIM   2048
#define NH    16
#define HD    128
#define EPS   1e-6f

typedef _Float16 f16x8 __attribute__((ext_vector_type(8)));
typedef _Float16 f16x4 __attribute__((ext_vector_type(4)));
typedef _Float16 f16x2 __attribute__((ext_vector_type(2)));
typedef float    f32x4 __attribute__((ext_vector_type(4)));

#define MFMA_F16 __builtin_amdgcn_mfma_f32_16x16x32_f16

// ---------------------------------------------------------------------------
// fp32 -> fp16 (single), 4 el/thread.  Used for x AND W (round-6 proven: the
// absmax floor is fp16 activation quantization; W-lo and K-lo terms are
// below it).
// ---------------------------------------------------------------------------
__global__ __launch_bounds__(256) void cvt_f16(
    const float* __restrict__ in, _Float16* __restrict__ out) {
  int i = blockIdx.x * 256 + threadIdx.x;
  float4 v = ((const float4*)in)[i];
  f16x4 o;
  o[0] = (_Float16)v.x; o[1] = (_Float16)v.y;
  o[2] = (_Float16)v.z; o[3] = (_Float16)v.w;
  ((f16x4*)out)[i] = o;
}

// ---------------------------------------------------------------------------
// Single-pass fp16 MFMA GEMM:  C[M,N] = A[M,K] @ B[N,K]^T   (round-7 proven)
// BM=256 BN=128 BK=64, 8 waves (2x4), per-wave 128x32.
// ---------------------------------------------------------------------------
#define BM8 256
#define BN8 128

__global__ __launch_bounds__(512, 2) void gemm_1p(
    const _Float16* __restrict__ Ag, const _Float16* __restrict__ Bg,
    float* __restrict__ C, int M, int N, int K) {
  // stack rows: [0,256) = A, [256,384) = B; 64 f16 per row.
  __shared__ __align__(16) _Float16 smem[2][384][64];

  const int t = threadIdx.x;
  const int w = t >> 6, lane = t & 63;
  const int bm = blockIdx.y * BM8, bn = blockIdx.x * BN8;
  const int wr = (w >> 2) * 128;      // wave row offset (2 wave-rows)
  const int wc = (w & 3) * 32;        // wave col offset (4 wave-cols)
  const int quad = lane >> 4, c15 = lane & 15;

  const _Float16* baseA = Ag + (size_t)bm * K;
  const _Float16* baseB = Bg + (size_t)bn * K;

  const int lrow = lane >> 3;
  const int lswz = ((lane & 7) ^ lrow) * 8;    // f16 units

  const int col0 = (((0 * 4) + quad) ^ (c15 & 7)) * 8;   // ks=0
  const int col1 = (((1 * 4) + quad) ^ (c15 & 7)) * 8;   // ks=1

  f32x4 acc[8][2] = {};
  f16x8 a0[8], a1[8], b0[2], b1[2];

  // 48 staging chunks (A 32, B 16), 6 per wave; chunk = 8 rows x 128B.
#define STAGE_TILE(buf, kofs)                                                  \
  {                                                                            \
    _Pragma("unroll")                                                          \
    for (int e = 0; e < 6; ++e) {                                              \
      int c = w * 6 + e;                                                       \
      int rl = c * 8 + lrow;                                                   \
      const _Float16* g = (rl < 256) ? (baseA + (size_t)rl * K)                \
                                     : (baseB + (size_t)(rl - 256) * K);       \
      __builtin_amdgcn_global_load_lds(                                        \
          (const __attribute__((address_space(1))) unsigned int*)(g + (kofs) + lswz), \
          (__attribute__((address_space(3))) unsigned int*)(&smem[buf][c * 8][0]),    \
          16, 0, 0);                                                           \
    }                                                                          \
  }

#define LDA8(dst, colv, buf)                                                   \
  _Pragma("unroll")                                                            \
  for (int m2 = 0; m2 < 8; ++m2)                                               \
    dst[m2] = *(const f16x8*)(&smem[buf][wr + m2 * 16 + c15][colv]);

#define LDB2(dst, colv, buf)                                                   \
  _Pragma("unroll")                                                            \
  for (int n2 = 0; n2 < 2; ++n2)                                               \
    dst[n2] = *(const f16x8*)(&smem[buf][256 + wc + n2 * 16 + c15][colv]);

#define MF16(af, bf)                                                           \
  _Pragma("unroll")                                                            \
  for (int m2 = 0; m2 < 8; ++m2)                                               \
    _Pragma("unroll")                                                          \
    for (int n2 = 0; n2 < 2; ++n2)                                             \
      acc[m2][n2] = MFMA_F16(af[m2], bf[n2], acc[m2][n2], 0, 0, 0);

#define SB() __builtin_amdgcn_sched_barrier(0);

  STAGE_TILE(0, 0)                     // prologue: tile 0 -> buf0

  const int NT = K >> 6;               // 32 K-tiles
  for (int tt = 0; tt < NT; ++tt) {
    const int buf = tt & 1;
    asm volatile("s_waitcnt vmcnt(0)" ::: "memory");
    SB();
    __builtin_amdgcn_s_barrier();
    SB();
    if (tt + 1 < NT) { STAGE_TILE(1 - buf, (tt + 1) * 64) }
    SB();

    // ---- all 20 fragment reads, consumption order ----
    LDA8(a0, col0, buf);
    LDB2(b0, col0, buf);
    LDA8(a1, col1, buf);
    LDB2(b1, col1, buf);
    SB();

    // ---- 2 x 16-MFMA clusters ----
    __builtin_amdgcn_s_setprio(1);
    MF16(a0, b0);
    __builtin_amdgcn_s_setprio(0);
    SB();
    __builtin_amdgcn_s_setprio(1);
    MF16(a1, b1);
    __builtin_amdgcn_s_setprio(0);
  }

  // C/D layout: col = lane&15, row = (lane>>4)*4 + reg
  #pragma unroll
  for (int m2 = 0; m2 < 8; ++m2)
    #pragma unroll
    for (int n2 = 0; n2 < 2; ++n2) {
      int col = bn + wc + 16 * n2 + c15;
      #pragma unroll
      for (int r = 0; r < 4; ++r) {
        int row = bm + wr + 16 * m2 + quad * 4 + r;
        C[(size_t)row * N + col] = acc[m2][n2][r];
      }
    }
#undef STAGE_TILE
#undef LDA8
#undef LDB2
#undef MF16
#undef SB
}

// ---------------------------------------------------------------------------
// RMSNorm + RoPE on q,k of qkv[b,s,6144]; emits Q and K as single fp16,
// layout [b,h,s,d].  (Round-8: K-lo stream dropped — same error budget as
// the W-lo drop, below the fp16 activation-quantization floor.)
// ---------------------------------------------------------------------------
__global__ __launch_bounds__(256) void rmsrope_f16(
    const float* __restrict__ qkv, const float* __restrict__ cosb,
    const float* __restrict__ sinb, _Float16* __restrict__ Qg,
    _Float16* __restrict__ Kg) {
  const int blk = blockIdx.x;           // b*SEQ + s
  const int b = blk >> 11, s = blk & (SEQ - 1);
  const int wave = threadIdx.x >> 6, lane = threadIdx.x & 63;
  const float* base = qkv + (size_t)blk * (3 * DIM);
  const float c  = cosb[s * HD + 2 * lane];
  const float sn = sinb[s * HD + 2 * lane];
  #pragma unroll
  for (int h = wave; h < NH; h += 4) {
    float2 q = *(const float2*)(base + h * HD + 2 * lane);
    float2 k = *(const float2*)(base + DIM + h * HD + 2 * lane);
    float ssq = q.x * q.x + q.y * q.y;
    float ssk = k.x * k.x + k.y * k.y;
    #pragma unroll
    for (int off = 32; off >= 1; off >>= 1) {
      ssq += __shfl_xor(ssq, off, 64);
      ssk += __shfl_xor(ssk, off, 64);
    }
    float rq = rsqrtf(ssq * (1.0f / HD) + EPS);
    float rk = rsqrtf(ssk * (1.0f / HD) + EPS);
    float q1 = q.x * rq, q2 = q.y * rq;
    float k1 = k.x * rk, k2 = k.y * rk;
    float qy1 = q1 * c - q2 * sn, qy2 = q1 * sn + q2 * c;
    float ky1 = k1 * c - k2 * sn, ky2 = k1 * sn + k2 * c;
    size_t o = ((size_t)(b * NH + h) * SEQ + s) * HD + 2 * lane;
    f16x2 qo, ko;
    qo[0] = (_Float16)qy1; qo[1] = (_Float16)qy2;
    ko[0] = (_Float16)ky1; ko[1] = (_Float16)ky2;
    *(f16x2*)(Qg + o) = qo;
    *(f16x2*)(Kg + o) = ko;
  }
}

// ---------------------------------------------------------------------------
// V transpose: qkv v-slice [64 s][128 d] fp32 -> Vt [b,h,d,s] single fp16.
// ---------------------------------------------------------------------------
__global__ __launch_bounds__(256) void vtrans_f16(
    const float* __restrict__ qkv, _Float16* __restrict__ Vt) {
  __shared__ _Float16 L[64 * 132];
  const int t = threadIdx.x;
  const int s0 = blockIdx.x * 64, h = blockIdx.y, b = blockIdx.z;
  const float* src = qkv + ((size_t)(b * SEQ + s0)) * (3 * DIM) + 2 * DIM + h * HD;
  #pragma unroll
  for (int it = 0; it < 8; ++it) {
    int f = t + it * 256;
    int r = f >> 5, c4 = f & 31;
    float4 v = *(const float4*)(src + (size_t)r * (3 * DIM) + c4 * 4);
    f16x4 o;
    o[0] = (_Float16)v.x; o[1] = (_Float16)v.y;
    o[2] = (_Float16)v.z; o[3] = (_Float16)v.w;
    *(f16x4*)(&L[r * 132 + c4 * 4]) = o;
  }
  __syncthreads();
  const int d = t >> 1, sc = (t & 1) * 32;
  size_t dst = ((size_t)((b * NH + h) * HD + d)) * SEQ + s0 + sc;
  #pragma unroll
  for (int j = 0; j < 8; ++j) {
    f16x4 o;
    o[0] = L[(sc + 4 * j + 0) * 132 + d];
    o[1] = L[(sc + 4 * j + 1) * 132 + d];
    o[2] = L[(sc + 4 * j + 2) * 132 + d];
    o[3] = L[(sc + 4 * j + 3) * 132 + d];
    *(f16x4*)(Vt + dst + j * 4) = o;
  }
}

// ---------------------------------------------------------------------------
// fp16 MFMA flash attention, fixed-max softmax.
// Round-8 changes (LDS-port wall: P b16 writes were 4-way conflicted, Kl
// pass doubled QK^T):
//  (a) single-pass K (Kl dropped): 32 MFMA/wave/iter (was 48), 18 ds_reads.
//  (b) K LDS rows staged PERMUTED: row r holds true kv rho(r)=2(r&15)+(r>>4)
//      (per-lane global source row — free).  S fragment (nf,c15) then maps
//      to storage col c' = 2*c15+nf, so softmax writes p0,p1 as ONE packed
//      f16x2 (16 b32 writes/iter, 2-way = free; was 32 b16 at 4-way).
//      V is already in c'=kv identity order -> PV unchanged.
// LDS f16 units: Kh[2] [0,8192)  Vt[2] [8192,16384)  P [16384,21504)
// per wave [32][40].  Q staging reuses [0,16384).
// ---------------------------------------------------------------------------
#define QT 128
#define KC 32

__global__ __launch_bounds__(256, 2) void flash_f16(
    const _Float16* __restrict__ Qg, const _Float16* __restrict__ Kg,
    const _Float16* __restrict__ Vtg, _Float16* __restrict__ Og) {
  __shared__ __align__(16) _Float16 sm[21504];

  const int t = threadIdx.x, w = t >> 6, lane = t & 63;
  const int quad = lane >> 4, c15 = lane & 15;
  // XCD swizzle: 64 blocks/XCD = 4 bh-groups x 16 q-chunks, so each head's
  // K/V stays in one XCD's L2 (16x reuse).
  const int bid = blockIdx.x;
  const int grp = (bid & 7) * 4 + ((bid >> 3) >> 4);   // 0..31 = b*NH+h
  const int qi  = (bid >> 3) & 15;
  const int bh = grp;
  const int hy = grp & (NH - 1), bz = grp >> 4;
  const int q0 = qi * QT;
  const int wr = w * 32;

  // ---- stage Q [128][128] f16 once; fragments -> registers ----
  {
    const _Float16* qsrc = Qg + ((size_t)bh * SEQ + q0) * HD;
    #pragma unroll
    for (int p = 0; p < 8; ++p) {
      int ci = p * 256 + t;
      int r = ci >> 4, c8 = (ci & 15) ^ (r & 15);
      __builtin_amdgcn_global_load_lds(
          (const __attribute__((address_space(1))) unsigned int*)(qsrc + (size_t)r * HD + c8 * 8),
          (__attribute__((address_space(3))) unsigned int*)(sm + ci * 8), 16, 0, 0);
    }
  }
  __syncthreads();
  f16x8 qf[2][4];  // [mf][ks]
  #pragma unroll
  for (int mf = 0; mf < 2; ++mf)
    #pragma unroll
    for (int ks = 0; ks < 4; ++ks) {
      int m = wr + mf * 16 + c15;
      int c8 = ks * 4 + quad;
      qf[mf][ks] = *(const f16x8*)(sm + (m * 16 + (c8 ^ (m & 15))) * 8);
    }
  // all waves' qf reads must retire before chunk staging overwrites [0,16384)
  asm volatile("s_waitcnt lgkmcnt(0)" ::: "memory");
  __builtin_amdgcn_sched_barrier(0);
  __syncthreads();

  float lrow[8];
  f32x4 oacc[2][8];
  #pragma unroll
  for (int i = 0; i < 8; ++i) lrow[i] = 0.f;
  #pragma unroll
  for (int mf = 0; mf < 2; ++mf)
    #pragma unroll
    for (int nf = 0; nf < 8; ++nf) oacc[mf][nf] = (f32x4){0.f, 0.f, 0.f, 0.f};

  const float sl = 0.12751744f;       // (1/sqrt(128)) * log2(e)
  const float M2 = 16.322231f;        // sqrt(128) * log2(e)  (|score|<=sqrt(128))
  _Float16* Pw = sm + 16384 + w * 1280;

  // 16 chunk loads (K 8, Vt 8) spread 4 per wave; tile wave-uniform.
  // K rows staged permuted: LDS row r <- global row kk + 2*(r&15)+(r>>4).
#define STAGE_KV(buf, kk)                                                     \
  _Pragma("unroll")                                                           \
  for (int e = 0; e < 4; ++e) {                                               \
    int idx = w * 4 + e;                                                      \
    int tile = idx >> 3, p = idx & 7;                                         \
    int ci = p * 64 + lane;                                                   \
    if (tile == 0) {                                                          \
      int r = ci >> 4, c8 = (ci & 15) ^ (r & 15);                             \
      int rp = 2 * (r & 15) + (r >> 4);                                       \
      const _Float16* src = Kg +                                              \
          ((size_t)bh * SEQ + (kk) + rp) * HD + c8 * 8;                       \
      __builtin_amdgcn_global_load_lds(                                       \
          (const __attribute__((address_space(1))) unsigned int*)src,         \
          (__attribute__((address_space(3))) unsigned int*)                   \
              (sm + (buf) * 4096 + ci * 8), 16, 0, 0);                        \
    } else {                                                                  \
      int d = ci >> 2, c8 = (ci & 3) ^ (d & 3);                               \
      const _Float16* src = Vtg + (size_t)bh * HD * SEQ + (size_t)d * SEQ     \
          + (kk) + c8 * 8;                                                    \
      __builtin_amdgcn_global_load_lds(                                       \
          (const __attribute__((address_space(1))) unsigned int*)src,         \
          (__attribute__((address_space(3))) unsigned int*)                   \
              (sm + 8192 + (buf) * 4096 + ci * 8), 16, 0, 0);                 \
    }                                                                         \
  }

  STAGE_KV(0, 0)                       // prologue: chunk 0 -> buf0

  const int NC = SEQ / KC;             // 64
  for (int it = 0; it < NC; ++it) {
    const int cur = it & 1, cb0 = cur * 4096;
    asm volatile("s_waitcnt vmcnt(0)" ::: "memory");
    __builtin_amdgcn_sched_barrier(0);
    __builtin_amdgcn_s_barrier();
    __builtin_amdgcn_sched_barrier(0);
    if (it + 1 < NC) { STAGE_KV(1 - cur, (it + 1) * KC) }

    // ---- S = Q K^T (single pass) ----
    f32x4 accs[2][2] = {};
    #pragma unroll
    for (int nf = 0; nf < 2; ++nf) {
      f16x8 kh[4];
      #pragma unroll
      for (int ks = 0; ks < 4; ++ks) {
        int n = nf * 16 + c15;
        int c8 = ks * 4 + quad;
        kh[ks] = *(const f16x8*)(sm + cb0 + (n * 16 + (c8 ^ (n & 15))) * 8);
      }
      __builtin_amdgcn_s_setprio(1);
      #pragma unroll
      for (int ks = 0; ks < 4; ++ks) {
        accs[0][nf] = MFMA_F16(qf[0][ks], kh[ks], accs[0][nf], 0, 0, 0);
        accs[1][nf] = MFMA_F16(qf[1][ks], kh[ks], accs[1][nf], 0, 0, 0);
      }
      __builtin_amdgcn_s_setprio(0);
    }

    // ---- fixed-shift softmax weights; packed f16x2 P-write ----
    // S fragment (nf,c15) = true kv 2*c15+nf (K row permutation), so p0,p1
    // are adjacent storage cols -> one b32 write (2-way bank = free).
    #pragma unroll
    for (int mf = 0; mf < 2; ++mf)
      #pragma unroll
      for (int reg = 0; reg < 4; ++reg) {
        float p0 = exp2f(fmaf(accs[mf][0][reg], sl, -M2));
        float p1 = exp2f(fmaf(accs[mf][1][reg], sl, -M2));
        lrow[mf * 4 + reg] += p0 + p1;
        int prow = mf * 16 + quad * 4 + reg;
        f16x2 pp;
        pp[0] = (_Float16)p0; pp[1] = (_Float16)p1;
        *(f16x2*)(Pw + prow * 40 + 2 * c15) = pp;
      }

    // ---- O += P V (single pass; kv index = storage col = identity for V) ----
    f16x8 pa0 = *(const f16x8*)(Pw + (c15) * 40 + quad * 8);
    f16x8 pa1 = *(const f16x8*)(Pw + (16 + c15) * 40 + quad * 8);
    __builtin_amdgcn_s_setprio(1);
    #pragma unroll
    for (int nf = 0; nf < 8; ++nf) {
      int dd = nf * 16 + c15;
      int slot = (dd * 4 + (quad ^ (dd & 3))) * 8;
      f16x8 vv = *(const f16x8*)(sm + 8192 + cb0 + slot);
      oacc[0][nf] = MFMA_F16(pa0, vv, oacc[0][nf], 0, 0, 0);
      oacc[1][nf] = MFMA_F16(pa1, vv, oacc[1][nf], 0, 0, 0);
    }
    __builtin_amdgcn_s_setprio(0);
  }

  // ---- epilogue: denominator reduce + O write (single fp16) ----
  #pragma unroll
  for (int i = 0; i < 8; ++i) {
    float s = lrow[i];
    #pragma unroll
    for (int off = 8; off >= 1; off >>= 1) s += __shfl_xor(s, off, 64);
    lrow[i] = s;
  }
  #pragma unroll
  for (int mf = 0; mf < 2; ++mf)
    #pragma unroll
    for (int reg = 0; reg < 4; ++reg) {
      float inv = 1.0f / lrow[mf * 4 + reg];
      int row = q0 + wr + mf * 16 + quad * 4 + reg;
      size_t ob = ((size_t)bz * SEQ + row) * DIM + hy * HD + c15;
      #pragma unroll
      for (int nf = 0; nf < 8; ++nf)
        Og[ob + nf * 16] = (_Float16)(oacc[mf][nf][reg] * inv);
    }
#undef STAGE_KV
}

// ---------------------------------------------------------------------------
// Launch.  Workspace (<= 201 MB):
//   [0, 100663296)          qkv fp32 -> later O16 + Wph
//   R = +100663296:
//     pre-gemm1 : x16 [R,+16.7M)  Wh [R+16.7M,+25.2M)
//     post-gemm1: Q16 [R) K16 [R+16.7M) Vt [R+50.3M) (16.7M each)
//   O16 at ws[0,16.7M), Wph ws+16.7M (after qkv consumed).
// ---------------------------------------------------------------------------
extern "C" void kernel_launch(void* const* d_in, const int* in_sizes, int n_in,
                              void* d_out, int out_size, void* d_ws, size_t ws_size,
                              hipStream_t stream) {
  const float* x     = (const float*)d_in[0];
  const float* cosb  = (const float*)d_in[1];
  const float* sinb  = (const float*)d_in[2];
  const float* Wqkv  = (const float*)d_in[3];
  const float* Wproj = (const float*)d_in[4];
  float* out = (float*)d_out;

  char* ws = (char*)d_ws;
  float* qkv = (float*)ws;
  char* R = ws + 100663296;
  _Float16* x16 = (_Float16*)(R);
  _Float16* Wh  = (_Float16*)(R + 16777216);
  _Float16* Q16 = (_Float16*)(R);
  _Float16* K16 = (_Float16*)(R + 16777216);
  _Float16* Vt  = (_Float16*)(R + 50331648);
  _Float16* O16 = (_Float16*)(ws);
  _Float16* Wph = (_Float16*)(ws + 16777216);

  cvt_f16<<<8192,  256, 0, stream>>>(x, x16);
  cvt_f16<<<12288, 256, 0, stream>>>(Wqkv, Wh);
  gemm_1p<<<dim3(48, 16), 512, 0, stream>>>(x16, Wh, qkv, 4096, 6144, 2048);
  rmsrope_f16<<<4096, 256, 0, stream>>>(qkv, cosb, sinb, Q16, K16);
  vtrans_f16<<<dim3(32, NH, BATCH), 256, 0, stream>>>(qkv, Vt);
  cvt_f16<<<4096, 256, 0, stream>>>(Wproj, Wph);   // after qkv consumed
  flash_f16<<<512, 256, 0, stream>>>(Q16, K16, Vt, O16);
  gemm_1p<<<dim3(16, 16), 512, 0, stream>>>(O16, Wph, out, 4096, 2048, 2048);
}

// Round 9
// 414.040 us; speedup vs baseline: 1.5768x; 1.0218x over previous
//
#include <hip/hip_runtime.h>
#include <math.h>

// Problem constants
#define BATCH 2
#define SEQ   2048
#define DIM   2048
#define NH    16
#define HD    128
#define EPS   1e-6f

typedef _Float16 f16x8 __attribute__((ext_vector_type(8)));
typedef _Float16 f16x4 __attribute__((ext_vector_type(4)));
typedef _Float16 f16x2 __attribute__((ext_vector_type(2)));
typedef float    f32x4 __attribute__((ext_vector_type(4)));

#define MFMA_F16 __builtin_amdgcn_mfma_f32_16x16x32_f16

// ---------------------------------------------------------------------------
// fp32 -> fp16 (single), 4 el/thread.
// ---------------------------------------------------------------------------
__global__ __launch_bounds__(256) void cvt_f16(
    const float* __restrict__ in, _Float16* __restrict__ out) {
  int i = blockIdx.x * 256 + threadIdx.x;
  float4 v = ((const float4*)in)[i];
  f16x4 o;
  o[0] = (_Float16)v.x; o[1] = (_Float16)v.y;
  o[2] = (_Float16)v.z; o[3] = (_Float16)v.w;
  ((f16x4*)out)[i] = o;
}

// ---------------------------------------------------------------------------
// Single-pass fp16 MFMA GEMM with CROSS-TILE register pipelining.
//   C[M,N] = A[M,K] @ B[N,K]^T
// Round-9: BM=128 BN=256 BK=64, 8 waves (2x4), per-wave 64x64.
// Why: rounds 1/4/5 proved the tile wall = LDS-port time + MFMA time IN
// SERIES whenever MFMA clusters depend on same-phase reads (1 block/CU,
// lockstep waves).  Now each phase issues the NEXT half-tile's 8 ds_reads
// alongside 16 MFMAs on fragments read LAST phase — no dependency, reads
// get a full MFMA cluster (~620cy) to land.  Per-wave 64x64 also cuts
// reads/MFMA 0.625 -> 0.5.  Grids exact: QKV (24,32)=768=3/CU, proj
// (8,32)=256=1/CU.  LDS 2x384x64 f16 = 96 KiB; XOR-8 swizzle kept (128B
// rows).  MFMA order identical to round-8 -> bit-identical output.
// ---------------------------------------------------------------------------
__global__ __launch_bounds__(512, 2) void gemm_1p(
    const _Float16* __restrict__ Ag, const _Float16* __restrict__ Bg,
    float* __restrict__ C, int M, int N, int K) {
  // stack rows: [0,128) = A, [128,384) = B; 64 f16 per row.
  __shared__ __align__(16) _Float16 smem[2][384][64];

  const int t = threadIdx.x;
  const int w = t >> 6, lane = t & 63;
  const int bm = blockIdx.y * 128, bn = blockIdx.x * 256;
  const int wr = (w >> 2) * 64;       // wave row offset (2 wave-rows)
  const int wc = (w & 3) * 64;        // wave col offset (4 wave-cols)
  const int quad = lane >> 4, c15 = lane & 15;

  const _Float16* baseA = Ag + (size_t)bm * K;
  const _Float16* baseB = Bg + (size_t)bn * K;

  const int lrow = lane >> 3;
  const int lswz = ((lane & 7) ^ lrow) * 8;    // f16 units

  const int col0 = ((0 + quad) ^ (c15 & 7)) * 8;   // ks=0
  const int col1 = ((4 + quad) ^ (c15 & 7)) * 8;   // ks=1

  f32x4 acc[4][4] = {};
  f16x8 a0[4], b0[4], a1[4], b1[4];   // two fragment sets (ks0 / ks1)

  // 48 staging chunks (A 16, B 32), 6 per wave; chunk = 8 rows x 128B.
#define STAGE_TILE(buf, kofs)                                                  \
  {                                                                            \
    _Pragma("unroll")                                                          \
    for (int e = 0; e < 6; ++e) {                                              \
      int c = w * 6 + e;                                                       \
      int rl = c * 8 + lrow;                                                   \
      const _Float16* g = (rl < 128) ? (baseA + (size_t)rl * K)                \
                                     : (baseB + (size_t)(rl - 128) * K);       \
      __builtin_amdgcn_global_load_lds(                                        \
          (const __attribute__((address_space(1))) unsigned int*)(g + (kofs) + lswz), \
          (__attribute__((address_space(3))) unsigned int*)(&smem[buf][c * 8][0]),    \
          16, 0, 0);                                                           \
    }                                                                          \
  }

  // one half-tile fragment set: 4 A + 4 B ds_read_b128
#define RD(dstA, dstB, colv, buf)                                              \
  _Pragma("unroll")                                                            \
  for (int m2 = 0; m2 < 4; ++m2)                                               \
    dstA[m2] = *(const f16x8*)(&smem[buf][wr + m2 * 16 + c15][colv]);          \
  _Pragma("unroll")                                                            \
  for (int n2 = 0; n2 < 4; ++n2)                                               \
    dstB[n2] = *(const f16x8*)(&smem[buf][128 + wc + n2 * 16 + c15][colv]);

#define MM(af, bf)                                                             \
  _Pragma("unroll")                                                            \
  for (int m2 = 0; m2 < 4; ++m2)                                               \
    _Pragma("unroll")                                                          \
    for (int n2 = 0; n2 < 4; ++n2)                                             \
      acc[m2][n2] = MFMA_F16(af[m2], bf[n2], acc[m2][n2], 0, 0, 0);

#define SB() __builtin_amdgcn_sched_barrier(0);

  // ---- prologue: tile 0 -> buf0; tile 1 in flight; ks0(0) frags loaded ----
  STAGE_TILE(0, 0)
  asm volatile("s_waitcnt vmcnt(0)" ::: "memory");
  SB();
  __builtin_amdgcn_s_barrier();
  SB();
  STAGE_TILE(1, 64)
  RD(a0, b0, col0, 0);

  const int NT = K >> 6;               // 32 K-tiles
  for (int tt = 0; tt < NT; ++tt) {
    const int buf = tt & 1;
    // ---- phase A: read ks1(tt)  ||  MFMA ks0(tt) (read last phase) ----
    RD(a1, b1, col1, buf);
    __builtin_amdgcn_s_setprio(1);
    MM(a0, b0);
    __builtin_amdgcn_s_setprio(0);
    // ---- phase B: barrier; stage tt+2; read ks0(tt+1)  ||  MFMA ks1(tt) ----
    asm volatile("s_waitcnt lgkmcnt(0)" ::: "memory");   // ks1 reads retired
    asm volatile("s_waitcnt vmcnt(0)" ::: "memory");     // tile tt+1 landed
    SB();
    __builtin_amdgcn_s_barrier();
    SB();
    if (tt + 2 < NT) { STAGE_TILE(buf, (tt + 2) * 64) }
    if (tt + 1 < NT) { RD(a0, b0, col0, 1 - buf); }
    __builtin_amdgcn_s_setprio(1);
    MM(a1, b1);
    __builtin_amdgcn_s_setprio(0);
  }

  // C/D layout: col = lane&15, row = (lane>>4)*4 + reg
  #pragma unroll
  for (int m2 = 0; m2 < 4; ++m2)
    #pragma unroll
    for (int n2 = 0; n2 < 4; ++n2) {
      int col = bn + wc + 16 * n2 + c15;
      #pragma unroll
      for (int r = 0; r < 4; ++r) {
        int row = bm + wr + 16 * m2 + quad * 4 + r;
        C[(size_t)row * N + col] = acc[m2][n2][r];
      }
    }
#undef STAGE_TILE
#undef RD
#undef MM
#undef SB
}

// ---------------------------------------------------------------------------
// RMSNorm + RoPE on q,k of qkv[b,s,6144]; emits Q and K as single fp16,
// layout [b,h,s,d].
// ---------------------------------------------------------------------------
__global__ __launch_bounds__(256) void rmsrope_f16(
    const float* __restrict__ qkv, const float* __restrict__ cosb,
    const float* __restrict__ sinb, _Float16* __restrict__ Qg,
    _Float16* __restrict__ Kg) {
  const int blk = blockIdx.x;           // b*SEQ + s
  const int b = blk >> 11, s = blk & (SEQ - 1);
  const int wave = threadIdx.x >> 6, lane = threadIdx.x & 63;
  const float* base = qkv + (size_t)blk * (3 * DIM);
  const float c  = cosb[s * HD + 2 * lane];
  const float sn = sinb[s * HD + 2 * lane];
  #pragma unroll
  for (int h = wave; h < NH; h += 4) {
    float2 q = *(const float2*)(base + h * HD + 2 * lane);
    float2 k = *(const float2*)(base + DIM + h * HD + 2 * lane);
    float ssq = q.x * q.x + q.y * q.y;
    float ssk = k.x * k.x + k.y * k.y;
    #pragma unroll
    for (int off = 32; off >= 1; off >>= 1) {
      ssq += __shfl_xor(ssq, off, 64);
      ssk += __shfl_xor(ssk, off, 64);
    }
    float rq = rsqrtf(ssq * (1.0f / HD) + EPS);
    float rk = rsqrtf(ssk * (1.0f / HD) + EPS);
    float q1 = q.x * rq, q2 = q.y * rq;
    float k1 = k.x * rk, k2 = k.y * rk;
    float qy1 = q1 * c - q2 * sn, qy2 = q1 * sn + q2 * c;
    float ky1 = k1 * c - k2 * sn, ky2 = k1 * sn + k2 * c;
    size_t o = ((size_t)(b * NH + h) * SEQ + s) * HD + 2 * lane;
    f16x2 qo, ko;
    qo[0] = (_Float16)qy1; qo[1] = (_Float16)qy2;
    ko[0] = (_Float16)ky1; ko[1] = (_Float16)ky2;
    *(f16x2*)(Qg + o) = qo;
    *(f16x2*)(Kg + o) = ko;
  }
}

// ---------------------------------------------------------------------------
// V transpose: qkv v-slice [64 s][128 d] fp32 -> Vt [b,h,d,s] single fp16.
// ---------------------------------------------------------------------------
__global__ __launch_bounds__(256) void vtrans_f16(
    const float* __restrict__ qkv, _Float16* __restrict__ Vt) {
  __shared__ _Float16 L[64 * 132];
  const int t = threadIdx.x;
  const int s0 = blockIdx.x * 64, h = blockIdx.y, b = blockIdx.z;
  const float* src = qkv + ((size_t)(b * SEQ + s0)) * (3 * DIM) + 2 * DIM + h * HD;
  #pragma unroll
  for (int it = 0; it < 8; ++it) {
    int f = t + it * 256;
    int r = f >> 5, c4 = f & 31;
    float4 v = *(const float4*)(src + (size_t)r * (3 * DIM) + c4 * 4);
    f16x4 o;
    o[0] = (_Float16)v.x; o[1] = (_Float16)v.y;
    o[2] = (_Float16)v.z; o[3] = (_Float16)v.w;
    *(f16x4*)(&L[r * 132 + c4 * 4]) = o;
  }
  __syncthreads();
  const int d = t >> 1, sc = (t & 1) * 32;
  size_t dst = ((size_t)((b * NH + h) * HD + d)) * SEQ + s0 + sc;
  #pragma unroll
  for (int j = 0; j < 8; ++j) {
    f16x4 o;
    o[0] = L[(sc + 4 * j + 0) * 132 + d];
    o[1] = L[(sc + 4 * j + 1) * 132 + d];
    o[2] = L[(sc + 4 * j + 2) * 132 + d];
    o[3] = L[(sc + 4 * j + 3) * 132 + d];
    *(f16x4*)(Vt + dst + j * 4) = o;
  }
}

// ---------------------------------------------------------------------------
// fp16 MFMA flash attention, fixed-max softmax (round-8 state, unchanged
// this round — isolating the GEMM change; flash will surface in top-5 for
// counters next round).
// LDS f16 units: K[2] [0,8192)  Vt[2] [8192,16384)  P [16384,21504)
// per wave [32][40].  Q staging reuses [0,16384).
// ---------------------------------------------------------------------------
#define QT 128
#define KC 32

__global__ __launch_bounds__(256, 2) void flash_f16(
    const _Float16* __restrict__ Qg, const _Float16* __restrict__ Kg,
    const _Float16* __restrict__ Vtg, _Float16* __restrict__ Og) {
  __shared__ __align__(16) _Float16 sm[21504];

  const int t = threadIdx.x, w = t >> 6, lane = t & 63;
  const int quad = lane >> 4, c15 = lane & 15;
  const int bid = blockIdx.x;
  const int grp = (bid & 7) * 4 + ((bid >> 3) >> 4);   // 0..31 = b*NH+h
  const int qi  = (bid >> 3) & 15;
  const int bh = grp;
  const int hy = grp & (NH - 1), bz = grp >> 4;
  const int q0 = qi * QT;
  const int wr = w * 32;

  // ---- stage Q [128][128] f16 once; fragments -> registers ----
  {
    const _Float16* qsrc = Qg + ((size_t)bh * SEQ + q0) * HD;
    #pragma unroll
    for (int p = 0; p < 8; ++p) {
      int ci = p * 256 + t;
      int r = ci >> 4, c8 = (ci & 15) ^ (r & 15);
      __builtin_amdgcn_global_load_lds(
          (const __attribute__((address_space(1))) unsigned int*)(qsrc + (size_t)r * HD + c8 * 8),
          (__attribute__((address_space(3))) unsigned int*)(sm + ci * 8), 16, 0, 0);
    }
  }
  __syncthreads();
  f16x8 qf[2][4];  // [mf][ks]
  #pragma unroll
  for (int mf = 0; mf < 2; ++mf)
    #pragma unroll
    for (int ks = 0; ks < 4; ++ks) {
      int m = wr + mf * 16 + c15;
      int c8 = ks * 4 + quad;
      qf[mf][ks] = *(const f16x8*)(sm + (m * 16 + (c8 ^ (m & 15))) * 8);
    }
  asm volatile("s_waitcnt lgkmcnt(0)" ::: "memory");
  __builtin_amdgcn_sched_barrier(0);
  __syncthreads();

  float lrow[8];
  f32x4 oacc[2][8];
  #pragma unroll
  for (int i = 0; i < 8; ++i) lrow[i] = 0.f;
  #pragma unroll
  for (int mf = 0; mf < 2; ++mf)
    #pragma unroll
    for (int nf = 0; nf < 8; ++nf) oacc[mf][nf] = (f32x4){0.f, 0.f, 0.f, 0.f};

  const float sl = 0.12751744f;       // (1/sqrt(128)) * log2(e)
  const float M2 = 16.322231f;        // sqrt(128) * log2(e)
  _Float16* Pw = sm + 16384 + w * 1280;

#define STAGE_KV(buf, kk)                                                     \
  _Pragma("unroll")                                                           \
  for (int e = 0; e < 4; ++e) {                                               \
    int idx = w * 4 + e;                                                      \
    int tile = idx >> 3, p = idx & 7;                                         \
    int ci = p * 64 + lane;                                                   \
    if (tile == 0) {                                                          \
      int r = ci >> 4, c8 = (ci & 15) ^ (r & 15);                             \
      int rp = 2 * (r & 15) + (r >> 4);                                       \
      const _Float16* src = Kg +                                              \
          ((size_t)bh * SEQ + (kk) + rp) * HD + c8 * 8;                       \
      __builtin_amdgcn_global_load_lds(                                       \
          (const __attribute__((address_space(1))) unsigned int*)src,         \
          (__attribute__((address_space(3))) unsigned int*)                   \
              (sm + (buf) * 4096 + ci * 8), 16, 0, 0);                        \
    } else {                                                                  \
      int d = ci >> 2, c8 = (ci & 3) ^ (d & 3);                               \
      const _Float16* src = Vtg + (size_t)bh * HD * SEQ + (size_t)d * SEQ     \
          + (kk) + c8 * 8;                                                    \
      __builtin_amdgcn_global_load_lds(                                       \
          (const __attribute__((address_space(1))) unsigned int*)src,         \
          (__attribute__((address_space(3))) unsigned int*)                   \
              (sm + 8192 + (buf) * 4096 + ci * 8), 16, 0, 0);                 \
    }                                                                         \
  }

  STAGE_KV(0, 0)                       // prologue: chunk 0 -> buf0

  const int NC = SEQ / KC;             // 64
  for (int it = 0; it < NC; ++it) {
    const int cur = it & 1, cb0 = cur * 4096;
    asm volatile("s_waitcnt vmcnt(0)" ::: "memory");
    __builtin_amdgcn_sched_barrier(0);
    __builtin_amdgcn_s_barrier();
    __builtin_amdgcn_sched_barrier(0);
    if (it + 1 < NC) { STAGE_KV(1 - cur, (it + 1) * KC) }

    // ---- S = Q K^T (single pass) ----
    f32x4 accs[2][2] = {};
    #pragma unroll
    for (int nf = 0; nf < 2; ++nf) {
      f16x8 kh[4];
      #pragma unroll
      for (int ks = 0; ks < 4; ++ks) {
        int n = nf * 16 + c15;
        int c8 = ks * 4 + quad;
        kh[ks] = *(const f16x8*)(sm + cb0 + (n * 16 + (c8 ^ (n & 15))) * 8);
      }
      __builtin_amdgcn_s_setprio(1);
      #pragma unroll
      for (int ks = 0; ks < 4; ++ks) {
        accs[0][nf] = MFMA_F16(qf[0][ks], kh[ks], accs[0][nf], 0, 0, 0);
        accs[1][nf] = MFMA_F16(qf[1][ks], kh[ks], accs[1][nf], 0, 0, 0);
      }
      __builtin_amdgcn_s_setprio(0);
    }

    // ---- fixed-shift softmax weights; packed f16x2 P-write ----
    #pragma unroll
    for (int mf = 0; mf < 2; ++mf)
      #pragma unroll
      for (int reg = 0; reg < 4; ++reg) {
        float p0 = exp2f(fmaf(accs[mf][0][reg], sl, -M2));
        float p1 = exp2f(fmaf(accs[mf][1][reg], sl, -M2));
        lrow[mf * 4 + reg] += p0 + p1;
        int prow = mf * 16 + quad * 4 + reg;
        f16x2 pp;
        pp[0] = (_Float16)p0; pp[1] = (_Float16)p1;
        *(f16x2*)(Pw + prow * 40 + 2 * c15) = pp;
      }

    // ---- O += P V ----
    f16x8 pa0 = *(const f16x8*)(Pw + (c15) * 40 + quad * 8);
    f16x8 pa1 = *(const f16x8*)(Pw + (16 + c15) * 40 + quad * 8);
    __builtin_amdgcn_s_setprio(1);
    #pragma unroll
    for (int nf = 0; nf < 8; ++nf) {
      int dd = nf * 16 + c15;
      int slot = (dd * 4 + (quad ^ (dd & 3))) * 8;
      f16x8 vv = *(const f16x8*)(sm + 8192 + cb0 + slot);
      oacc[0][nf] = MFMA_F16(pa0, vv, oacc[0][nf], 0, 0, 0);
      oacc[1][nf] = MFMA_F16(pa1, vv, oacc[1][nf], 0, 0, 0);
    }
    __builtin_amdgcn_s_setprio(0);
  }

  // ---- epilogue: denominator reduce + O write (single fp16) ----
  #pragma unroll
  for (int i = 0; i < 8; ++i) {
    float s = lrow[i];
    #pragma unroll
    for (int off = 8; off >= 1; off >>= 1) s += __shfl_xor(s, off, 64);
    lrow[i] = s;
  }
  #pragma unroll
  for (int mf = 0; mf < 2; ++mf)
    #pragma unroll
    for (int reg = 0; reg < 4; ++reg) {
      float inv = 1.0f / lrow[mf * 4 + reg];
      int row = q0 + wr + mf * 16 + quad * 4 + reg;
      size_t ob = ((size_t)bz * SEQ + row) * DIM + hy * HD + c15;
      #pragma unroll
      for (int nf = 0; nf < 8; ++nf)
        Og[ob + nf * 16] = (_Float16)(oacc[mf][nf][reg] * inv);
    }
#undef STAGE_KV
}

// ---------------------------------------------------------------------------
// Launch.  Workspace (<= 201 MB):
//   [0, 100663296)          qkv fp32 -> later O16 + Wph
//   R = +100663296:
//     pre-gemm1 : x16 [R,+16.7M)  Wh [R+16.7M,+25.2M)
//     post-gemm1: Q16 [R) K16 [R+16.7M) Vt [R+50.3M) (16.7M each)
//   O16 at ws[0,16.7M), Wph ws+16.7M (after qkv consumed).
// ---------------------------------------------------------------------------
extern "C" void kernel_launch(void* const* d_in, const int* in_sizes, int n_in,
                              void* d_out, int out_size, void* d_ws, size_t ws_size,
                              hipStream_t stream) {
  const float* x     = (const float*)d_in[0];
  const float* cosb  = (const float*)d_in[1];
  const float* sinb  = (const float*)d_in[2];
  const float* Wqkv  = (const float*)d_in[3];
  const float* Wproj = (const float*)d_in[4];
  float* out = (float*)d_out;

  char* ws = (char*)d_ws;
  float* qkv = (float*)ws;
  char* R = ws + 100663296;
  _Float16* x16 = (_Float16*)(R);
  _Float16* Wh  = (_Float16*)(R + 16777216);
  _Float16* Q16 = (_Float16*)(R);
  _Float16* K16 = (_Float16*)(R + 16777216);
  _Float16* Vt  = (_Float16*)(R + 50331648);
  _Float16* O16 = (_Float16*)(ws);
  _Float16* Wph = (_Float16*)(ws + 16777216);

  cvt_f16<<<8192,  256, 0, stream>>>(x, x16);
  cvt_f16<<<12288, 256, 0, stream>>>(Wqkv, Wh);
  gemm_1p<<<dim3(24, 32), 512, 0, stream>>>(x16, Wh, qkv, 4096, 6144, 2048);
  rmsrope_f16<<<4096, 256, 0, stream>>>(qkv, cosb, sinb, Q16, K16);
  vtrans_f16<<<dim3(32, NH, BATCH), 256, 0, stream>>>(qkv, Vt);
  cvt_f16<<<4096, 256, 0, stream>>>(Wproj, Wph);   // after qkv consumed
  flash_f16<<<512, 256, 0, stream>>>(Q16, K16, Vt, O16);
  gemm_1p<<<dim3(8, 32), 512, 0, stream>>>(O16, Wph, out, 4096, 2048, 2048);
}

// Round 11
// 398.859 us; speedup vs baseline: 1.6368x; 1.0381x over previous
//
#include <hip/hip_runtime.h>
#include <math.h>

// Problem constants
#define BATCH 2
#define SEQ   2048
#define DIM   2048
#define NH    16
#define HD    128
#define EPS   1e-6f

typedef _Float16 f16x8 __attribute__((ext_vector_type(8)));
typedef _Float16 f16x4 __attribute__((ext_vector_type(4)));
typedef _Float16 f16x2 __attribute__((ext_vector_type(2)));
typedef float    f32x4 __attribute__((ext_vector_type(4)));

#define MFMA_F16 __builtin_amdgcn_mfma_f32_16x16x32_f16

// ---------------------------------------------------------------------------
// One conversion kernel for all three fp32->fp16 inputs (x, Wqkv, Wproj).
// Round-10: merged to cut launch gaps (8 kernels -> 5 total).
// ---------------------------------------------------------------------------
__global__ __launch_bounds__(256) void cvt_all(
    const float* __restrict__ x, const float* __restrict__ wqkv,
    const float* __restrict__ wproj, _Float16* __restrict__ x16,
    _Float16* __restrict__ wh, _Float16* __restrict__ wph) {
  int bid = blockIdx.x;
  const float* in;
  _Float16* out;
  int i;
  if (bid < 8192)       { in = x;     out = x16; i = bid; }
  else if (bid < 20480) { in = wqkv;  out = wh;  i = bid - 8192; }
  else                  { in = wproj; out = wph; i = bid - 20480; }
  int j = i * 256 + threadIdx.x;
  float4 v = ((const float4*)in)[j];
  f16x4 o;
  o[0] = (_Float16)v.x; o[1] = (_Float16)v.y;
  o[2] = (_Float16)v.z; o[3] = (_Float16)v.w;
  ((f16x4*)out)[j] = o;
}

// ---------------------------------------------------------------------------
// Single-pass fp16 MFMA GEMM, cross-tile register pipelining (round-9
// structure, proven 114us QKV).  Round-10: output type templated — QKV GEMM
// writes fp16 (halves WRITE_SIZE; error below the measured 4.88e-4
// activation-quantization floor), proj writes fp32.
// BM=128 BN=256 BK=64, 8 waves (2x4), per-wave 64x64.  LDS 96 KiB, XOR-8
// swizzle (zero conflicts).
// ---------------------------------------------------------------------------
template <typename OT>
__global__ __launch_bounds__(512, 2) void gemm_1p(
    const _Float16* __restrict__ Ag, const _Float16* __restrict__ Bg,
    OT* __restrict__ C, int M, int N, int K) {
  // stack rows: [0,128) = A, [128,384) = B; 64 f16 per row.
  __shared__ __align__(16) _Float16 smem[2][384][64];

  const int t = threadIdx.x;
  const int w = t >> 6, lane = t & 63;
  const int bm = blockIdx.y * 128, bn = blockIdx.x * 256;
  const int wr = (w >> 2) * 64;       // wave row offset (2 wave-rows)
  const int wc = (w & 3) * 64;        // wave col offset (4 wave-cols)
  const int quad = lane >> 4, c15 = lane & 15;

  const _Float16* baseA = Ag + (size_t)bm * K;
  const _Float16* baseB = Bg + (size_t)bn * K;

  const int lrow = lane >> 3;
  const int lswz = ((lane & 7) ^ lrow) * 8;    // f16 units

  const int col0 = ((0 + quad) ^ (c15 & 7)) * 8;   // ks=0
  const int col1 = ((4 + quad) ^ (c15 & 7)) * 8;   // ks=1

  f32x4 acc[4][4] = {};
  f16x8 a0[4], b0[4], a1[4], b1[4];   // two fragment sets (ks0 / ks1)

  // 48 staging chunks (A 16, B 32), 6 per wave; chunk = 8 rows x 128B.
#define STAGE_TILE(buf, kofs)                                                  \
  {                                                                            \
    _Pragma("unroll")                                                          \
    for (int e = 0; e < 6; ++e) {                                              \
      int c = w * 6 + e;                                                       \
      int rl = c * 8 + lrow;                                                   \
      const _Float16* g = (rl < 128) ? (baseA + (size_t)rl * K)                \
                                     : (baseB + (size_t)(rl - 128) * K);       \
      __builtin_amdgcn_global_load_lds(                                        \
          (const __attribute__((address_space(1))) unsigned int*)(g + (kofs) + lswz), \
          (__attribute__((address_space(3))) unsigned int*)(&smem[buf][c * 8][0]),    \
          16, 0, 0);                                                           \
    }                                                                          \
  }

  // one half-tile fragment set: 4 A + 4 B ds_read_b128
#define RD(dstA, dstB, colv, buf)                                              \
  _Pragma("unroll")                                                            \
  for (int m2 = 0; m2 < 4; ++m2)                                               \
    dstA[m2] = *(const f16x8*)(&smem[buf][wr + m2 * 16 + c15][colv]);          \
  _Pragma("unroll")                                                            \
  for (int n2 = 0; n2 < 4; ++n2)                                               \
    dstB[n2] = *(const f16x8*)(&smem[buf][128 + wc + n2 * 16 + c15][colv]);

#define MM(af, bf)                                                             \
  _Pragma("unroll")                                                            \
  for (int m2 = 0; m2 < 4; ++m2)                                               \
    _Pragma("unroll")                                                          \
    for (int n2 = 0; n2 < 4; ++n2)                                             \
      acc[m2][n2] = MFMA_F16(af[m2], bf[n2], acc[m2][n2], 0, 0, 0);

#define SB() __builtin_amdgcn_sched_barrier(0);

  // ---- prologue: tile 0 -> buf0; tile 1 in flight; ks0(0) frags loaded ----
  STAGE_TILE(0, 0)
  asm volatile("s_waitcnt vmcnt(0)" ::: "memory");
  SB();
  __builtin_amdgcn_s_barrier();
  SB();
  STAGE_TILE(1, 64)
  RD(a0, b0, col0, 0);

  const int NT = K >> 6;               // 32 K-tiles
  for (int tt = 0; tt < NT; ++tt) {
    const int buf = tt & 1;
    // ---- phase A: read ks1(tt)  ||  MFMA ks0(tt) (read last phase) ----
    RD(a1, b1, col1, buf);
    __builtin_amdgcn_s_setprio(1);
    MM(a0, b0);
    __builtin_amdgcn_s_setprio(0);
    // ---- phase B: barrier; stage tt+2; read ks0(tt+1)  ||  MFMA ks1(tt) ----
    asm volatile("s_waitcnt lgkmcnt(0)" ::: "memory");   // ks1 reads retired
    asm volatile("s_waitcnt vmcnt(0)" ::: "memory");     // tile tt+1 landed
    SB();
    __builtin_amdgcn_s_barrier();
    SB();
    if (tt + 2 < NT) { STAGE_TILE(buf, (tt + 2) * 64) }
    if (tt + 1 < NT) { RD(a0, b0, col0, 1 - buf); }
    __builtin_amdgcn_s_setprio(1);
    MM(a1, b1);
    __builtin_amdgcn_s_setprio(0);
  }

  // C/D layout: col = lane&15, row = (lane>>4)*4 + reg
  #pragma unroll
  for (int m2 = 0; m2 < 4; ++m2)
    #pragma unroll
    for (int n2 = 0; n2 < 4; ++n2) {
      int col = bn + wc + 16 * n2 + c15;
      #pragma unroll
      for (int r = 0; r < 4; ++r) {
        int row = bm + wr + 16 * m2 + quad * 4 + r;
        C[(size_t)row * N + col] = (OT)acc[m2][n2][r];
      }
    }
#undef STAGE_TILE
#undef RD
#undef MM
#undef SB
}

// ---------------------------------------------------------------------------
// Merged RMSNorm+RoPE (blocks [0,4096)) and V-transpose (blocks [4096,5120)).
// qkv is now fp16 [b,s,3*DIM].  Emits Q,K fp16 [b,h,s,d] and Vt fp16
// [b,h,d,s].  Round-10: merged to cut a launch gap; input reads halved.
// ---------------------------------------------------------------------------
__global__ __launch_bounds__(256) void rope_vtrans(
    const _Float16* __restrict__ qkv, const float* __restrict__ cosb,
    const float* __restrict__ sinb, _Float16* __restrict__ Qg,
    _Float16* __restrict__ Kg, _Float16* __restrict__ Vt) {
  __shared__ _Float16 L[64 * 132];
  const int bid = blockIdx.x;
  const int t = threadIdx.x;
  if (bid < 4096) {
    // ---- RMSNorm + RoPE on one (b,s) row ----
    const int b = bid >> 11, s = bid & (SEQ - 1);
    const int wave = t >> 6, lane = t & 63;
    const _Float16* base = qkv + (size_t)bid * (3 * DIM);
    const float c  = cosb[s * HD + 2 * lane];
    const float sn = sinb[s * HD + 2 * lane];
    #pragma unroll
    for (int h = wave; h < NH; h += 4) {
      f16x2 qv = *(const f16x2*)(base + h * HD + 2 * lane);
      f16x2 kv = *(const f16x2*)(base + DIM + h * HD + 2 * lane);
      float qx = (float)qv[0], qy = (float)qv[1];
      float kx = (float)kv[0], ky = (float)kv[1];
      float ssq = qx * qx + qy * qy;
      float ssk = kx * kx + ky * ky;
      #pragma unroll
      for (int off = 32; off >= 1; off >>= 1) {
        ssq += __shfl_xor(ssq, off, 64);
        ssk += __shfl_xor(ssk, off, 64);
      }
      float rq = rsqrtf(ssq * (1.0f / HD) + EPS);
      float rk = rsqrtf(ssk * (1.0f / HD) + EPS);
      float q1 = qx * rq, q2 = qy * rq;
      float k1 = kx * rk, k2 = ky * rk;
      float qy1 = q1 * c - q2 * sn, qy2 = q1 * sn + q2 * c;
      float ky1 = k1 * c - k2 * sn, ky2 = k1 * sn + k2 * c;
      size_t o = ((size_t)(b * NH + h) * SEQ + s) * HD + 2 * lane;
      f16x2 qo, ko;
      qo[0] = (_Float16)qy1; qo[1] = (_Float16)qy2;
      ko[0] = (_Float16)ky1; ko[1] = (_Float16)ky2;
      *(f16x2*)(Qg + o) = qo;
      *(f16x2*)(Kg + o) = ko;
    }
  } else {
    // ---- V transpose: [64 s][128 d] fp16 -> Vt [b,h,d,s] ----
    const int vb = bid - 4096;                  // 0..1023
    const int s0 = (vb & 31) * 64, h = (vb >> 5) & 15, b = vb >> 9;
    const _Float16* src =
        qkv + ((size_t)(b * SEQ + s0)) * (3 * DIM) + 2 * DIM + h * HD;
    #pragma unroll
    for (int it = 0; it < 4; ++it) {
      int f = t + it * 256;
      int r = f >> 4, c8 = f & 15;
      f16x8 v = *(const f16x8*)(src + (size_t)r * (3 * DIM) + c8 * 8);
      *(f16x8*)(&L[r * 132 + c8 * 8]) = v;
    }
    __syncthreads();
    const int d = t >> 1, sc = (t & 1) * 32;
    size_t dst = ((size_t)((b * NH + h) * HD + d)) * SEQ + s0 + sc;
    #pragma unroll
    for (int j = 0; j < 8; ++j) {
      f16x4 o;
      o[0] = L[(sc + 4 * j + 0) * 132 + d];
      o[1] = L[(sc + 4 * j + 1) * 132 + d];
      o[2] = L[(sc + 4 * j + 2) * 132 + d];
      o[3] = L[(sc + 4 * j + 3) * 132 + d];
      *(f16x4*)(Vt + dst + j * 4) = o;
    }
  }
}

// ---------------------------------------------------------------------------
// fp16 MFMA flash attention, fixed-max softmax (round-8/9 state, unchanged).
// LDS f16 units: K[2] [0,8192)  Vt[2] [8192,16384)  P [16384,21504)
// per wave [32][40].  Q staging reuses [0,16384).
// ---------------------------------------------------------------------------
#define QT 128
#define KC 32

__global__ __launch_bounds__(256, 2) void flash_f16(
    const _Float16* __restrict__ Qg, const _Float16* __restrict__ Kg,
    const _Float16* __restrict__ Vtg, _Float16* __restrict__ Og) {
  __shared__ __align__(16) _Float16 sm[21504];

  const int t = threadIdx.x, w = t >> 6, lane = t & 63;
  const int quad = lane >> 4, c15 = lane & 15;
  const int bid = blockIdx.x;
  const int grp = (bid & 7) * 4 + ((bid >> 3) >> 4);   // 0..31 = b*NH+h
  const int qi  = (bid >> 3) & 15;
  const int bh = grp;
  const int hy = grp & (NH - 1), bz = grp >> 4;
  const int q0 = qi * QT;
  const int wr = w * 32;

  // ---- stage Q [128][128] f16 once; fragments -> registers ----
  {
    const _Float16* qsrc = Qg + ((size_t)bh * SEQ + q0) * HD;
    #pragma unroll
    for (int p = 0; p < 8; ++p) {
      int ci = p * 256 + t;
      int r = ci >> 4, c8 = (ci & 15) ^ (r & 15);
      __builtin_amdgcn_global_load_lds(
          (const __attribute__((address_space(1))) unsigned int*)(qsrc + (size_t)r * HD + c8 * 8),
          (__attribute__((address_space(3))) unsigned int*)(sm + ci * 8), 16, 0, 0);
    }
  }
  __syncthreads();
  f16x8 qf[2][4];  // [mf][ks]
  #pragma unroll
  for (int mf = 0; mf < 2; ++mf)
    #pragma unroll
    for (int ks = 0; ks < 4; ++ks) {
      int m = wr + mf * 16 + c15;
      int c8 = ks * 4 + quad;
      qf[mf][ks] = *(const f16x8*)(sm + (m * 16 + (c8 ^ (m & 15))) * 8);
    }
  asm volatile("s_waitcnt lgkmcnt(0)" ::: "memory");
  __builtin_amdgcn_sched_barrier(0);
  __syncthreads();

  float lrow[8];
  f32x4 oacc[2][8];
  #pragma unroll
  for (int i = 0; i < 8; ++i) lrow[i] = 0.f;
  #pragma unroll
  for (int mf = 0; mf < 2; ++mf)
    #pragma unroll
    for (int nf = 0; nf < 8; ++nf) oacc[mf][nf] = (f32x4){0.f, 0.f, 0.f, 0.f};

  const float sl = 0.12751744f;       // (1/sqrt(128)) * log2(e)
  const float M2 = 16.322231f;        // sqrt(128) * log2(e)
  _Float16* Pw = sm + 16384 + w * 1280;

#define STAGE_KV(buf, kk)                                                     \
  _Pragma("unroll")                                                           \
  for (int e = 0; e < 4; ++e) {                                               \
    int idx = w * 4 + e;                                                      \
    int tile = idx >> 3, p = idx & 7;                                         \
    int ci = p * 64 + lane;                                                   \
    if (tile == 0) {                                                          \
      int r = ci >> 4, c8 = (ci & 15) ^ (r & 15);                             \
      int rp = 2 * (r & 15) + (r >> 4);                                       \
      const _Float16* src = Kg +                                              \
          ((size_t)bh * SEQ + (kk) + rp) * HD + c8 * 8;                       \
      __builtin_amdgcn_global_load_lds(                                       \
          (const __attribute__((address_space(1))) unsigned int*)src,         \
          (__attribute__((address_space(3))) unsigned int*)                   \
              (sm + (buf) * 4096 + ci * 8), 16, 0, 0);                        \
    } else {                                                                  \
      int d = ci >> 2, c8 = (ci & 3) ^ (d & 3);                               \
      const _Float16* src = Vtg + (size_t)bh * HD * SEQ + (size_t)d * SEQ     \
          + (kk) + c8 * 8;                                                    \
      __builtin_amdgcn_global_load_lds(                                       \
          (const __attribute__((address_space(1))) unsigned int*)src,         \
          (__attribute__((address_space(3))) unsigned int*)                   \
              (sm + 8192 + (buf) * 4096 + ci * 8), 16, 0, 0);                 \
    }                                                                         \
  }

  STAGE_KV(0, 0)                       // prologue: chunk 0 -> buf0

  const int NC = SEQ / KC;             // 64
  for (int it = 0; it < NC; ++it) {
    const int cur = it & 1, cb0 = cur * 4096;
    asm volatile("s_waitcnt vmcnt(0)" ::: "memory");
    __builtin_amdgcn_sched_barrier(0);
    __builtin_amdgcn_s_barrier();
    __builtin_amdgcn_sched_barrier(0);
    if (it + 1 < NC) { STAGE_KV(1 - cur, (it + 1) * KC) }

    // ---- S = Q K^T (single pass) ----
    f32x4 accs[2][2] = {};
    #pragma unroll
    for (int nf = 0; nf < 2; ++nf) {
      f16x8 kh[4];
      #pragma unroll
      for (int ks = 0; ks < 4; ++ks) {
        int n = nf * 16 + c15;
        int c8 = ks * 4 + quad;
        kh[ks] = *(const f16x8*)(sm + cb0 + (n * 16 + (c8 ^ (n & 15))) * 8);
      }
      __builtin_amdgcn_s_setprio(1);
      #pragma unroll
      for (int ks = 0; ks < 4; ++ks) {
        accs[0][nf] = MFMA_F16(qf[0][ks], kh[ks], accs[0][nf], 0, 0, 0);
        accs[1][nf] = MFMA_F16(qf[1][ks], kh[ks], accs[1][nf], 0, 0, 0);
      }
      __builtin_amdgcn_s_setprio(0);
    }

    // ---- fixed-shift softmax weights; packed f16x2 P-write ----
    #pragma unroll
    for (int mf = 0; mf < 2; ++mf)
      #pragma unroll
      for (int reg = 0; reg < 4; ++reg) {
        float p0 = exp2f(fmaf(accs[mf][0][reg], sl, -M2));
        float p1 = exp2f(fmaf(accs[mf][1][reg], sl, -M2));
        lrow[mf * 4 + reg] += p0 + p1;
        int prow = mf * 16 + quad * 4 + reg;
        f16x2 pp;
        pp[0] = (_Float16)p0; pp[1] = (_Float16)p1;
        *(f16x2*)(Pw + prow * 40 + 2 * c15) = pp;
      }

    // ---- O += P V ----
    f16x8 pa0 = *(const f16x8*)(Pw + (c15) * 40 + quad * 8);
    f16x8 pa1 = *(const f16x8*)(Pw + (16 + c15) * 40 + quad * 8);
    __builtin_amdgcn_s_setprio(1);
    #pragma unroll
    for (int nf = 0; nf < 8; ++nf) {
      int dd = nf * 16 + c15;
      int slot = (dd * 4 + (quad ^ (dd & 3))) * 8;
      f16x8 vv = *(const f16x8*)(sm + 8192 + cb0 + slot);
      oacc[0][nf] = MFMA_F16(pa0, vv, oacc[0][nf], 0, 0, 0);
      oacc[1][nf] = MFMA_F16(pa1, vv, oacc[1][nf], 0, 0, 0);
    }
    __builtin_amdgcn_s_setprio(0);
  }

  // ---- epilogue: denominator reduce + O write (single fp16) ----
  #pragma unroll
  for (int i = 0; i < 8; ++i) {
    float s = lrow[i];
    #pragma unroll
    for (int off = 8; off >= 1; off >>= 1) s += __shfl_xor(s, off, 64);
    lrow[i] = s;
  }
  #pragma unroll
  for (int mf = 0; mf < 2; ++mf)
    #pragma unroll
    for (int reg = 0; reg < 4; ++reg) {
      float inv = 1.0f / lrow[mf * 4 + reg];
      int row = q0 + wr + mf * 16 + quad * 4 + reg;
      size_t ob = ((size_t)bz * SEQ + row) * DIM + hy * HD + c15;
      #pragma unroll
      for (int nf = 0; nf < 8; ++nf)
        Og[ob + nf * 16] = (_Float16)(oacc[mf][nf][reg] * inv);
    }
#undef STAGE_KV
}

// ---------------------------------------------------------------------------
// Launch.  Workspace (<= 168 MB):
//   qkv16 (fp16) at ws[0, 50.3M); O16 reuses ws[0, 16.7M) after qkv consumed.
//   R = ws + 100663296:
//     x16 [R, +16.7M)  Wh [R+16.7M, +25.2M -> ends R+41.9M)
//     Wph [R+41.9M, +8.4M -> ends R+50.3M)   (written up-front by cvt_all)
//     post-gemm1: Q16 [R)  K16 [R+16.7M)  Vt [R+50.3M, +16.7M)
// ---------------------------------------------------------------------------
extern "C" void kernel_launch(void* const* d_in, const int* in_sizes, int n_in,
                              void* d_out, int out_size, void* d_ws, size_t ws_size,
                              hipStream_t stream) {
  const float* x     = (const float*)d_in[0];
  const float* cosb  = (const float*)d_in[1];
  const float* sinb  = (const float*)d_in[2];
  const float* Wqkv  = (const float*)d_in[3];
  const float* Wproj = (const float*)d_in[4];
  float* out = (float*)d_out;

  char* ws = (char*)d_ws;
  _Float16* qkv16 = (_Float16*)ws;
  char* R = ws + 100663296;
  _Float16* x16 = (_Float16*)(R);
  _Float16* Wh  = (_Float16*)(R + 16777216);
  _Float16* Wph = (_Float16*)(R + 41943040);
  _Float16* Q16 = (_Float16*)(R);
  _Float16* K16 = (_Float16*)(R + 16777216);
  _Float16* Vt  = (_Float16*)(R + 50331648);
  _Float16* O16 = (_Float16*)(ws);

  cvt_all<<<24576, 256, 0, stream>>>(x, Wqkv, Wproj, x16, Wh, Wph);
  gemm_1p<_Float16><<<dim3(24, 32), 512, 0, stream>>>(x16, Wh, qkv16, 4096, 6144, 2048);
  rope_vtrans<<<5120, 256, 0, stream>>>(qkv16, cosb, sinb, Q16, K16, Vt);
  flash_f16<<<512, 256, 0, stream>>>(Q16, K16, Vt, O16);
  gemm_1p<float><<<dim3(8, 32), 512, 0, stream>>>(O16, Wph, out, 4096, 2048, 2048);
}